// Round 11
// baseline (8131.616 us; speedup 1.0000x reference)
//
#include <hip/hip_runtime.h>

typedef unsigned short u16;
typedef unsigned int u32;
typedef unsigned long long u64;
typedef __attribute__((ext_vector_type(8))) short s16x8;
typedef __attribute__((ext_vector_type(4))) short s16x4;
typedef __attribute__((ext_vector_type(4))) float f32x4;
typedef __attribute__((ext_vector_type(2))) float f32x2;

#define TSTEPS 1024
#define URS    648                         // u_sh row stride u16: [inpA 64 | inpB 64 | h 512 | pad 8]
#define ZOFF   ((size_t)134217728)         // 256*1024*512
#define CZOFF  (ZOFF + 131072)             // + 256*512

// workspace layout (bytes)
// hbu: tagged h exchange units, u64 = [tag32 | 2x bf16]. 2 bufs x 256 rows x 256 units = 1 MB
#define HBU_OFF 0
#define WK_OFF  1048576                    // packed weights 2048*576 u16
#define WX_OFF  3407872                    // x-weights 2048*2 f32
#define WB_OFF  3424256                    // bias 2048 f32
#define AW_OFF  3432448                    // alpha/hx weights 4*512 u16
#define AB_OFF  3436544                    // alpha/hx biases 4 f32

__device__ __forceinline__ float bf2f(u16 h) { union { unsigned u; float f; } c; c.u = ((unsigned)h) << 16; return c.f; }
__device__ __forceinline__ u16 f2bf(float f) { union { float f; unsigned u; } c; c.f = f; unsigned u = c.u; return (u16)((u + 0x7FFFu + ((u >> 16) & 1u)) >> 16); }
__device__ __forceinline__ float fsigm(float x) { return __builtin_amdgcn_rcpf(1.f + __builtin_amdgcn_exp2f(-1.44269504089f * x)); }
__device__ __forceinline__ float ftanh(float x) { float t = __builtin_amdgcn_exp2f(2.88539008178f * x); return 1.f - 2.f * __builtin_amdgcn_rcpf(t + 1.f); }
__device__ __forceinline__ float pick4(float a, float b, float c, float d, int m) {
  return (m == 0) ? a : (m == 1) ? b : (m == 2) ? c : d;
}
#define NTS(p, v) __builtin_nontemporal_store((v), (p))
#define ALD(p) __hip_atomic_load((p), __ATOMIC_RELAXED, __HIP_MEMORY_SCOPE_AGENT)
#define AST(p, v) __hip_atomic_store((p), (v), __ATOMIC_RELAXED, __HIP_MEMORY_SCOPE_AGENT)

#if defined(__has_builtin)
#if __has_builtin(__builtin_amdgcn_fdot2_f32_bf16)
#define HAVE_DOT2 1
typedef __bf16 bf16x2 __attribute__((ext_vector_type(2)));
#endif
#endif

__device__ __forceinline__ float dot2acc(u32 h2, u32 a2, float acc) {
#ifdef HAVE_DOT2
  bf16x2 hv, av;
  __builtin_memcpy(&hv, &h2, 4);
  __builtin_memcpy(&av, &a2, 4);
  return __builtin_amdgcn_fdot2_f32_bf16(hv, av, acc, false);
#else
  acc += bf2f((u16)(h2 & 0xFFFFu)) * bf2f((u16)(a2 & 0xFFFFu));
  acc += bf2f((u16)(h2 >> 16)) * bf2f((u16)(a2 >> 16));
  return acc;
#endif
}

// ---------------- prep: pack weights (bf16, j-major gate interleave) ----------------
__global__ void prep_pack(const float* __restrict__ W_w, const float* __restrict__ W_b,
                          const float* __restrict__ U_w, const float* __restrict__ alpha_w,
                          const float* __restrict__ alpha_b, const float* __restrict__ hx_w,
                          const float* __restrict__ hx_b,
                          u16* __restrict__ wk, float* __restrict__ wx, float* __restrict__ wb,
                          u16* __restrict__ aw, float* __restrict__ ab)
{
  int n = blockIdx.x;
  int tid = threadIdx.x;
  if (n < 2048) {
    int j = n >> 2, g = n & 3;
    bool real = (j < 510);
    int row = g * 510 + j;
    for (int k = tid; k < 576; k += 64) {
      float v = 0.f;
      if (real) {
        if (k < 64) v = W_w[row * 66 + 2 + k];
        else { int kk = k - 64; v = (kk < 510) ? U_w[row * 510 + kk] : 0.f; }
      }
      wk[(size_t)n * 576 + k] = f2bf(v);
    }
    if (tid == 0) {
      wx[n * 2 + 0] = real ? W_w[row * 66 + 0] : 0.f;
      wx[n * 2 + 1] = real ? W_w[row * 66 + 1] : 0.f;
      wb[n] = real ? W_b[row] : 0.f;
    }
  } else {
    int s = n - 2048; // 0,1: alpha rows; 2,3: hx rows
    for (int j = tid; j < 512; j += 64) {
      float v = 0.f;
      if (j < 510) v = (s < 2) ? alpha_w[s * 510 + j] : hx_w[(s - 2) * 510 + j];
      aw[s * 512 + j] = f2bf(v);
    }
    if (tid == 0) ab[s] = (s < 2) ? alpha_b[s] : hx_b[s - 2];
  }
}

// ---------------- prep: tagged h(0) into buffer 0 (tag 0); invalidate buffer 1 tags ----------------
// Re-run on every graph replay -> kills cross-replay tag ABA and poison.
__global__ void prep_hinit(const float* __restrict__ z0, u64* __restrict__ hbu)
{
  int b = blockIdx.x;
  int u = threadIdx.x;             // unit u covers cols 2u, 2u+1
  int j2 = u * 2;
  u32 pv = 0;
  if (j2 < 510) {
    u16 lo = f2bf(z0[(size_t)b * 512 + 2 + j2]);
    u16 hi = (j2 + 1 < 510) ? f2bf(z0[(size_t)b * 512 + 3 + j2]) : (u16)0;
    pv = (u32)lo | ((u32)hi << 16);
  }
  AST(&hbu[(size_t)b * 256 + u], (u64)pv);                                 // tag 0 = h(0)
  AST(&hbu[65536 + (size_t)b * 256 + u], 0xFFFFFFFF00000000ull);           // invalid tag
}

// ---------------- persistent LSTM kernel ----------------
// grid 256 = 16 groups x 16 WGs; group = bid&15, w = bid>>4 owns gate cols [w*128, w*128+128)
// h exchange: SELF-VALIDATING 8B units [tag32|2xbf16] via relaxed sc0/sc1 agent atomics.
// Consumer spins loading its 16 units and checks embedded tags == t: when the tag matches,
// the h in the SAME atomic word is valid -> no flag/data race, no drain, no stamp, no
// arrive barrier. Drift safety: publishing tag t+2 over buffer p requires the producer's
// spin for t+1 to have passed, which requires ALL WGs published t+1, which requires all
// finished reading h(t) -> overwrite-before-read impossible; '==' cannot deadlock.
// One __syncthreads per step (LDS staging); u_sh input region parity-buffered.
extern "C" __global__ void __launch_bounds__(256, 1)
lstm_persist(const float* __restrict__ rnn, const float* __restrict__ tau,
             const float* __restrict__ z0, const float* __restrict__ cz0,
             const u16* __restrict__ wk, const float* __restrict__ wx, const float* __restrict__ wb,
             const u16* __restrict__ aw, const float* __restrict__ ab,
             u64* __restrict__ hbu, float* __restrict__ out)
{
  __shared__ u16   u_sh[16 * URS];
  __shared__ float xs_sh[2][32];

  const int tid = threadIdx.x;
  const int bid = blockIdx.x;
  const int grp = bid & 15;
  const int w   = bid >> 4;
  const int bb0 = grp * 16;
  const int v   = tid >> 6;
  const int l   = tid & 63;
  const int l15 = l & 15, l4 = l >> 4;
  const int n0  = w * 128 + v * 32;
  const int prow = tid >> 4;
  const int jc   = tid & 15;

  // alpha/hx weights persistent in registers
  u32 awr[4][4][4];
  {
    const u32* awp = (const u32*)aw;
#pragma unroll
    for (int s = 0; s < 4; ++s)
#pragma unroll
      for (int q = 0; q < 4; ++q)
#pragma unroll
        for (int p = 0; p < 4; ++p)
          awr[s][q][p] = awp[(s * 512 + jc * 32 + q * 8) / 2 + p];
  }
  float ab0 = ab[0], ab1 = ab[1], ab2 = ab[2], ab3 = ab[3];

  // persistent B fragments: wave holds its 32 gate-cols x full K in VGPRs
  s16x8 bfr[36];
  {
    const u16* wb0 = wk + (size_t)(n0 + l15) * 576 + l4 * 8;
#pragma unroll
    for (int kf = 0; kf < 18; ++kf) {
      bfr[2 * kf + 0] = *(const s16x8*)(wb0 + kf * 32);
      bfr[2 * kf + 1] = *(const s16x8*)(wb0 + 16 * 576 + kf * 32);
    }
  }
  float wxf[2][2], wbf[2];
  {
    int nA = n0 + l15, nB = nA + 16;
    wxf[0][0] = wx[nA * 2]; wxf[0][1] = wx[nA * 2 + 1];
    wxf[1][0] = wx[nB * 2]; wxf[1][1] = wx[nB * 2 + 1];
    wbf[0] = wb[nA]; wbf[1] = wb[nB];
  }
  float cst[2][4];
#pragma unroll
  for (int nf = 0; nf < 2; ++nf) {
    int j = (n0 + nf * 16 + l15) >> 2;
#pragma unroll
    for (int r = 0; r < 4; ++r) {
      int b = bb0 + 4 * l4 + r;
      cst[nf][r] = (j < 510) ? cz0[(size_t)b * 512 + 2 + j] : 0.f;
    }
  }
  // stage input(0) into inp parity-region 0
  {
    const float* ip = rnn + (size_t)(bb0 + prow) * (TSTEPS * 64) + jc * 4;
    float4 inpv = *(const float4*)ip;
    s16x4 iv;
    iv[0] = (short)f2bf(inpv.x); iv[1] = (short)f2bf(inpv.y);
    iv[2] = (short)f2bf(inpv.z); iv[3] = (short)f2bf(inpv.w);
    *(s16x4*)(&u_sh[prow * URS + jc * 4]) = iv;
  }
  __syncthreads();

  // epilogue activation constants (gate g==2 is tanh, others sigmoid; tanh(x)=2*sigm(2x)-1)
  const int g = l & 3;
  const float sc_a = (g == 2) ? -2.88539008178f : -1.44269504089f;
  const float sc_m = (g == 2) ? 2.f : 1.f;
  const float sc_c = (g == 2) ? -1.f : 0.f;

  float tv_reg = 0.f;   // tau[b][t-1], prefetched in previous shadow

  for (int t = 0; t <= TSTEPS; ++t) {
    const int cur = t & 1;
    // ---- spin-load h(t): 16 self-validating units; tag==t validates the word itself ----
    u64 un[16];
    {
      const u64* up = hbu + (size_t)cur * 65536 + ((size_t)(bb0 + prow) << 8) + jc * 16;
      const u32 expt = (u32)t;
      u32 pend = 0xFFFFu;
      while (pend) {
        u32 np = 0;
#pragma unroll
        for (int p = 0; p < 16; ++p) {
          if (pend & (1u << p)) {
            u64 uv = ALD(up + p);
            un[p] = uv;
            if ((u32)(uv >> 32) != expt) np |= (1u << p);
          }
        }
        pend = np;
      }
    }
    u32 h32[16];
#pragma unroll
    for (int p = 0; p < 16; ++p) h32[p] = (u32)un[p];

    // ---- out[t-1] h-part from registers (free now: nothing drains behind these) ----
    if (t >= 1 && prow == w) {
      float* ob = out + ((size_t)(bb0 + w) * TSTEPS + (t - 1)) * 512 + 2 + jc * 32;
#pragma unroll
      for (int p = 0; p < 16; ++p) {
        int col = jc * 32 + 2 * p;
        if (col < 510) {
          u32 h2 = h32[p];
          f32x2 fv;
          fv[0] = bf2f((u16)(h2 & 0xFFFFu));
          fv[1] = bf2f((u16)(h2 >> 16));
          NTS((f32x2*)(ob + 2 * p), fv);
        }
      }
    }

    // dots: s[4] = h(t) . {alpha0,alpha1,hx0,hx1}, then jc-reduce
    float s0 = 0.f, s1 = 0.f, s2 = 0.f, s3 = 0.f;
#pragma unroll
    for (int q = 0; q < 4; ++q) {
#pragma unroll
      for (int p = 0; p < 4; ++p) {
        u32 h2 = h32[4 * q + p];
        s0 = dot2acc(h2, awr[0][q][p], s0);
        s1 = dot2acc(h2, awr[1][q][p], s1);
        s2 = dot2acc(h2, awr[2][q][p], s2);
        s3 = dot2acc(h2, awr[3][q][p], s3);
      }
    }
#pragma unroll
    for (int m = 1; m <= 8; m <<= 1) {
      s0 += __shfl_xor(s0, m, 64);
      s1 += __shfl_xor(s1, m, 64);
      s2 += __shfl_xor(s2, m, 64);
      s3 += __shfl_xor(s3, m, 64);
    }
    // stage h(t) into u_sh h-region (offset 128)
    {
      u16* ur = &u_sh[prow * URS + 128 + jc * 32];
      u32 t4[4];
      t4[0] = h32[0];  t4[1] = h32[1];  t4[2] = h32[2];  t4[3] = h32[3];  __builtin_memcpy(ur + 0, t4, 16);
      t4[0] = h32[4];  t4[1] = h32[5];  t4[2] = h32[6];  t4[3] = h32[7];  __builtin_memcpy(ur + 8, t4, 16);
      t4[0] = h32[8];  t4[1] = h32[9];  t4[2] = h32[10]; t4[3] = h32[11]; __builtin_memcpy(ur + 16, t4, 16);
      t4[0] = h32[12]; t4[1] = h32[13]; t4[2] = h32[14]; t4[3] = h32[15]; __builtin_memcpy(ur + 24, t4, 16);
    }
    if ((l & 15) == 0) {   // one lane per batch row: x recursion
      int row = prow;
      float xn0, xn1;
      if (t == 0) {
        xn0 = z0[(size_t)(bb0 + row) * 512 + 0];
        xn1 = z0[(size_t)(bb0 + row) * 512 + 1];
      } else {
        float x0p = xs_sh[cur ^ 1][row * 2 + 0], x1p = xs_sh[cur ^ 1][row * 2 + 1];
        float tv = tv_reg;
        float a0v = fsigm(s0 + ab0);
        float a1v = fsigm(s1 + ab1);
        float hx0 = s2 + ab2, hx1 = s3 + ab3;
        float xm0 = x0p + tv * (1.5f * x0p - 1.5f * x1p);
        float xm1 = x1p + tv * (0.6666666667f * x0p);
        xn0 = (1.f - a0v) * xm0 + a0v * hx0;
        xn1 = (1.f - a1v) * xm1 + a1v * hx1;
      }
      xs_sh[cur][row * 2 + 0] = xn0; xs_sh[cur][row * 2 + 1] = xn1;
    }
    __syncthreads();   // the only per-step barrier: u_sh/xs_sh[cur] ready for all waves

    if (t == TSTEPS) {
      // final z outputs (out[TSTEPS-1] h-part already written from registers above)
      int j2 = tid * 2;
      if (j2 < 510) {
        unsigned hv2 = *(const unsigned*)&u_sh[w * URS + 128 + j2];
        float h0 = bf2f((u16)(hv2 & 0xFFFFu));
        float h1 = bf2f((u16)(hv2 >> 16));
        size_t zb = ZOFF + (size_t)(bb0 + w) * 512 + 2 + j2;
        NTS(&out[zb], h0); NTS(&out[zb + 1], h1);
      }
      if ((l & 15) == 0 && w == prow) {
        int b = bb0 + prow;
        float xn0 = xs_sh[cur][prow * 2 + 0], xn1 = xs_sh[cur][prow * 2 + 1];
        float* ob = out + ((size_t)b * TSTEPS + (TSTEPS - 1)) * 512;
        NTS(ob + 0, xn0); NTS(ob + 1, xn1);
        NTS(&out[ZOFF + (size_t)b * 512 + 0], xn0);
        NTS(&out[ZOFF + (size_t)b * 512 + 1], xn1);
        NTS(&out[CZOFF + (size_t)b * 512 + 0], cz0[(size_t)b * 512 + 0]);
        NTS(&out[CZOFF + (size_t)b * 512 + 1], cz0[(size_t)b * 512 + 1]);
      }
      break;
    }

    // ---- GEMM: M16 x N32(per wave) x K576, weights in registers ----
    f32x4 acc0 = {0.f, 0.f, 0.f, 0.f};
    f32x4 acc1 = {0.f, 0.f, 0.f, 0.f};
    {
      const u16* apF = &u_sh[l15 * URS + l4 * 8];
#pragma unroll
      for (int kf = 0; kf < 18; ++kf) {
        const u16* ap = (kf < 2) ? (apF + cur * 64 + kf * 32) : (apF + 64 + kf * 32);
        s16x8 a = *(const s16x8*)ap;
        acc0 = __builtin_amdgcn_mfma_f32_16x16x32_bf16(a, bfr[2 * kf + 0], acc0, 0, 0, 0);
        acc1 = __builtin_amdgcn_mfma_f32_16x16x32_bf16(a, bfr[2 * kf + 1], acc1, 0, 0, 0);
      }
    }
    // ---- epilogue: bias + rank-2 x-term, activate-own-col, gather, LSTM cell ----
    float xr[4][2];
#pragma unroll
    for (int r = 0; r < 4; ++r) {
      xr[r][0] = xs_sh[cur][(4 * l4 + r) * 2 + 0];
      xr[r][1] = xs_sh[cur][(4 * l4 + r) * 2 + 1];
    }
    float myh0 = 0.f, myh1 = 0.f;
#pragma unroll
    for (int nf = 0; nf < 2; ++nf) {
      f32x4 av = nf ? acc1 : acc0;
#pragma unroll
      for (int r = 0; r < 4; ++r) {
        float pre = av[r] + wbf[nf] + xr[r][0] * wxf[nf][0] + xr[r][1] * wxf[nf][1];
        float y = __builtin_amdgcn_rcpf(1.f + __builtin_amdgcn_exp2f(sc_a * pre));
        float act = y * sc_m + sc_c;
        float vB = __shfl_xor(act, 1, 64);
        float vC = __shfl_xor(act, 2, 64);
        float vD = __shfl_xor(vB, 2, 64);
        float si = pick4(act, vB, vC, vD, g);
        float sf = pick4(act, vB, vC, vD, g ^ 1);
        float tg = pick4(act, vB, vC, vD, g ^ 2);
        float so = pick4(act, vB, vC, vD, g ^ 3);
        float cn = sf * cst[nf][r] + si * tg;
        cst[nf][r] = cn;
        float hn = so * ftanh(cn);
        if (g == r) { if (nf == 0) myh0 = hn; else myh1 = hn; }
      }
    }
    // ---- publish h(t+1): tagged 8B units (2 cols + tag t+1), fire-and-forget ----
    {
      int row = 4 * l4 + g;
      u32 mine = (u32)f2bf(myh0) | ((u32)f2bf(myh1) << 16);
      u32 oth = (u32)__shfl_xor((int)mine, 4, 64);
      if (((l15 >> 2) & 1) == 0) {
        int j0 = (n0 >> 2) + (l15 >> 2);                       // even column index
        u32 v0 = (mine & 0xFFFFu) | ((oth & 0xFFFFu) << 16);   // cols j0, j0+1   (nf=0)
        u32 v1 = (mine >> 16) | (oth & 0xFFFF0000u);           // cols j0+4, j0+5 (nf=1)
        u64 tb = ((u64)(u32)(t + 1)) << 32;
        u64* hp = hbu + (size_t)(cur ^ 1) * 65536 + ((size_t)(bb0 + row) << 8);
        AST(hp + (j0 >> 1), tb | (u64)v0);
        AST(hp + (j0 >> 1) + 2, tb | (u64)v1);
      }
    }
    // ---- shadow: x out-write + input(t+1) -> inp parity-region + tau prefetch ----
    if (t >= 1 && (l & 15) == 0 && w == prow) {
      float* ob = out + ((size_t)(bb0 + prow) * TSTEPS + (t - 1)) * 512;
      NTS(ob + 0, xs_sh[cur][prow * 2 + 0]); NTS(ob + 1, xs_sh[cur][prow * 2 + 1]);
    }
    if (t + 1 < TSTEPS) {
      const float* ip = rnn + (size_t)(bb0 + prow) * (TSTEPS * 64) + (size_t)(t + 1) * 64 + jc * 4;
      float4 inpv = *(const float4*)ip;
      s16x4 iv;
      iv[0] = (short)f2bf(inpv.x); iv[1] = (short)f2bf(inpv.y);
      iv[2] = (short)f2bf(inpv.z); iv[3] = (short)f2bf(inpv.w);
      *(s16x4*)(&u_sh[prow * URS + ((t + 1) & 1) * 64 + jc * 4]) = iv;   // disjoint from inp[cur]
    }
    if ((l & 15) == 0) {
      tv_reg = tau[(size_t)(bb0 + prow) * TSTEPS + t];   // used as tau[b][(t+1)-1]
    }
  }

  // ---- final cell state: cz_fin[:, 2:512] = c(T) ----
#pragma unroll
  for (int nf = 0; nf < 2; ++nf) {
    int j = (n0 + nf * 16 + l15) >> 2;
    if (j < 510) {
#pragma unroll
      for (int r = 0; r < 4; ++r) {
        if ((l & 3) == r) {
          NTS(&out[CZOFF + (size_t)(bb0 + 4 * l4 + r) * 512 + 2 + j], cst[nf][r]);
        }
      }
    }
  }
}

extern "C" void kernel_launch(void* const* d_in, const int* in_sizes, int n_in,
                              void* d_out, int out_size, void* d_ws, size_t ws_size,
                              hipStream_t stream) {
  const float* rnn     = (const float*)d_in[0];
  const float* tau     = (const float*)d_in[1];
  const float* z0      = (const float*)d_in[2];
  const float* cz0     = (const float*)d_in[3];
  const float* W_w     = (const float*)d_in[4];
  const float* W_b     = (const float*)d_in[5];
  const float* U_w     = (const float*)d_in[6];
  const float* alpha_w = (const float*)d_in[7];
  const float* alpha_b = (const float*)d_in[8];
  const float* hx_w    = (const float*)d_in[9];
  const float* hx_b    = (const float*)d_in[10];

  char* ws = (char*)d_ws;
  u64*      hbu = (u64*)(ws + HBU_OFF);
  u16*      wkv = (u16*)(ws + WK_OFF);
  float*    wxv = (float*)(ws + WX_OFF);
  float*    wbv = (float*)(ws + WB_OFF);
  u16*      awv = (u16*)(ws + AW_OFF);
  float*    abv = (float*)(ws + AB_OFF);

  hipLaunchKernelGGL(prep_pack, dim3(2052), dim3(64), 0, stream,
                     W_w, W_b, U_w, alpha_w, alpha_b, hx_w, hx_b, wkv, wxv, wbv, awv, abv);
  hipLaunchKernelGGL(prep_hinit, dim3(256), dim3(256), 0, stream, z0, hbu);
  hipLaunchKernelGGL(lstm_persist, dim3(256), dim3(256), 0, stream,
                     rnn, tau, z0, cz0, wkv, wxv, wbv, awv, abv, hbu, (float*)d_out);
}

// Round 12
// 5185.258 us; speedup vs baseline: 1.5682x; 1.5682x over previous
//
#include <hip/hip_runtime.h>

typedef unsigned short u16;
typedef unsigned int u32;
typedef unsigned long long u64;
typedef __attribute__((ext_vector_type(8))) short s16x8;
typedef __attribute__((ext_vector_type(4))) short s16x4;
typedef __attribute__((ext_vector_type(4))) float f32x4;
typedef __attribute__((ext_vector_type(2))) float f32x2;
typedef __attribute__((ext_vector_type(4))) u32 u32x4;

#define TSTEPS 1024
#define URS    648                         // u_sh row stride u16: [inpA 64 | inpB 64 | h 512 | pad 8]
#define ZOFF   ((size_t)134217728)         // 256*1024*512
#define CZOFF  (ZOFF + 131072)             // + 256*512

// workspace layout (bytes)
#define MALL_OFF 0                         // 33 u32 lines x 64B: [0]=ready|ovf, [1..16]=claims, [17..32]=snapcnt
#define GC_OFF   4096                      // 16 group counters x 64B — NEVER zeroed (snapshot-based)
#define HB_OFF   8192                      // h double buffer: 2*256*512 u16
#define WK_OFF   (HB_OFF + 524288)         // packed weights 2048*576 u16
#define WX_OFF   (WK_OFF + 2359296)        // x-weights 2048*2 f32
#define WB_OFF   (WX_OFF + 16384)          // bias 2048 f32
#define AW_OFF   (WB_OFF + 8192)           // alpha/hx weights 4*512 u16
#define AB_OFF   (AW_OFF + 4096)           // alpha/hx biases 4 f32

__device__ __forceinline__ float bf2f(u16 h) { union { unsigned u; float f; } c; c.u = ((unsigned)h) << 16; return c.f; }
__device__ __forceinline__ u16 f2bf(float f) { union { float f; unsigned u; } c; c.f = f; unsigned u = c.u; return (u16)((u + 0x7FFFu + ((u >> 16) & 1u)) >> 16); }
__device__ __forceinline__ float fsigm(float x) { return __builtin_amdgcn_rcpf(1.f + __builtin_amdgcn_exp2f(-1.44269504089f * x)); }
__device__ __forceinline__ float ftanh(float x) { float t = __builtin_amdgcn_exp2f(2.88539008178f * x); return 1.f - 2.f * __builtin_amdgcn_rcpf(t + 1.f); }
__device__ __forceinline__ float pick4(float a, float b, float c, float d, int m) {
  return (m == 0) ? a : (m == 1) ? b : (m == 2) ? c : d;
}
#define NTS(p, v) __builtin_nontemporal_store((v), (p))

#if defined(__has_builtin)
#if __has_builtin(__builtin_amdgcn_fdot2_f32_bf16)
#define HAVE_DOT2 1
typedef __bf16 bf16x2 __attribute__((ext_vector_type(2)));
#endif
#endif

__device__ __forceinline__ float dot2acc(u32 h2, u32 a2, float acc) {
#ifdef HAVE_DOT2
  bf16x2 hv, av;
  __builtin_memcpy(&hv, &h2, 4);
  __builtin_memcpy(&av, &a2, 4);
  return __builtin_amdgcn_fdot2_f32_bf16(hv, av, acc, false);
#else
  acc += bf2f((u16)(h2 & 0xFFFFu)) * bf2f((u16)(a2 & 0xFFFFu));
  acc += bf2f((u16)(h2 >> 16)) * bf2f((u16)(a2 >> 16));
  return acc;
#endif
}

// ---- scope-templated exchange ops. M=1: XCD-local L2 (no sc1). M=0: MALL (sc1, r6-validated).
// ALL waits are atomic RMWs: atomics never complete in L1 -> no stale-L1 spin (r8's hang).
template<int M> __device__ __forceinline__ void cnt_add1(u32* p) {
  u32 one = 1u;
  if (M) asm volatile("global_atomic_add %0, %1, off" :: "v"(p), "v"(one) : "memory");
  else   asm volatile("global_atomic_add %0, %1, off sc1" :: "v"(p), "v"(one) : "memory");
}
template<int M> __device__ __forceinline__ u32 cnt_read(u32* p) {   // add-0, return old
  u32 r, z = 0;
  if (M) asm volatile("global_atomic_add %0, %1, %2, off sc0" : "=v"(r) : "v"(p), "v"(z) : "memory");
  else   asm volatile("global_atomic_add %0, %1, %2, off sc0 sc1" : "=v"(r) : "v"(p), "v"(z) : "memory");
  asm volatile("s_waitcnt vmcnt(0)" ::: "memory");
  __builtin_amdgcn_sched_barrier(0);
  return r;
}
template<int M> __device__ __forceinline__ void hstore(u32* p, u32 v) {
  if (M) asm volatile("global_store_dword %0, %1, off sc0" :: "v"(p), "v"(v) : "memory");
  else   asm volatile("global_store_dword %0, %1, off sc0 sc1" :: "v"(p), "v"(v) : "memory");
}
template<int M> __device__ __forceinline__ void hload4(const u16* p, u32x4& a) {
  if (M) asm volatile("global_load_dwordx4 %0, %1, off sc0" : "=v"(a) : "v"(p));
  else   asm volatile("global_load_dwordx4 %0, %1, off sc0 sc1" : "=v"(a) : "v"(p));
}

// ---------------- prep: pack weights; zero MALL sync lines (gcnt NOT zeroed) ----------------
__global__ void prep_pack(const float* __restrict__ W_w, const float* __restrict__ W_b,
                          const float* __restrict__ U_w, const float* __restrict__ alpha_w,
                          const float* __restrict__ alpha_b, const float* __restrict__ hx_w,
                          const float* __restrict__ hx_b,
                          u16* __restrict__ wk, float* __restrict__ wx, float* __restrict__ wb,
                          u16* __restrict__ aw, float* __restrict__ ab, u32* __restrict__ mall)
{
  int n = blockIdx.x;
  int tid = threadIdx.x;
  if (n < 2048) {
    int j = n >> 2, g = n & 3;
    bool real = (j < 510);
    int row = g * 510 + j;
    for (int k = tid; k < 576; k += 64) {
      float v = 0.f;
      if (real) {
        if (k < 64) v = W_w[row * 66 + 2 + k];
        else { int kk = k - 64; v = (kk < 510) ? U_w[row * 510 + kk] : 0.f; }
      }
      wk[(size_t)n * 576 + k] = f2bf(v);
    }
    if (tid == 0) {
      wx[n * 2 + 0] = real ? W_w[row * 66 + 0] : 0.f;
      wx[n * 2 + 1] = real ? W_w[row * 66 + 1] : 0.f;
      wb[n] = real ? W_b[row] : 0.f;
    }
    if (n == 0 && tid < 33)
      __hip_atomic_store(&mall[tid * 16], 0u, __ATOMIC_RELAXED, __HIP_MEMORY_SCOPE_AGENT);
  } else {
    int s = n - 2048; // 0,1: alpha rows; 2,3: hx rows
    for (int j = tid; j < 512; j += 64) {
      float v = 0.f;
      if (j < 510) v = (s < 2) ? alpha_w[s * 510 + j] : hx_w[(s - 2) * 510 + j];
      aw[s * 512 + j] = f2bf(v);
    }
    if (tid == 0) ab[s] = (s < 2) ? alpha_b[s] : hx_b[s - 2];
  }
}

// ---------------- persistent LSTM body (templated on exchange scope) ----------------
template<int M>
__device__ __forceinline__ void lstm_body(
    const float* __restrict__ rnn, const float* __restrict__ tau,
    const float* __restrict__ z0, const float* __restrict__ cz0,
    const u16* __restrict__ wk, const float* __restrict__ wx, const float* __restrict__ wb,
    const u16* __restrict__ aw, const float* __restrict__ ab,
    u16* __restrict__ hbuf, u32* gc, u32 cbase, float* __restrict__ out,
    int grp, int w, int tid,
    u16* u_sh, float (*xs_sh)[32])
{
  const int bb0 = grp * 16;
  const int l   = tid & 63;
  const int l15 = l & 15, l4 = l >> 4;
  const int v   = tid >> 6;
  const int n0  = w * 128 + v * 32;
  const int prow = tid >> 4;
  const int jc   = tid & 15;

  // alpha/hx weights persistent in registers
  u32 awr[4][4][4];
  {
    const u32* awp = (const u32*)aw;
#pragma unroll
    for (int s = 0; s < 4; ++s)
#pragma unroll
      for (int q = 0; q < 4; ++q)
#pragma unroll
        for (int p = 0; p < 4; ++p)
          awr[s][q][p] = awp[(s * 512 + jc * 32 + q * 8) / 2 + p];
  }
  float ab0 = ab[0], ab1 = ab[1], ab2 = ab[2], ab3 = ab[3];

  // persistent B fragments
  s16x8 bfr[36];
  {
    const u16* wb0 = wk + (size_t)(n0 + l15) * 576 + l4 * 8;
#pragma unroll
    for (int kf = 0; kf < 18; ++kf) {
      bfr[2 * kf + 0] = *(const s16x8*)(wb0 + kf * 32);
      bfr[2 * kf + 1] = *(const s16x8*)(wb0 + 16 * 576 + kf * 32);
    }
  }
  float wxf[2][2], wbf[2];
  {
    int nA = n0 + l15, nB = nA + 16;
    wxf[0][0] = wx[nA * 2]; wxf[0][1] = wx[nA * 2 + 1];
    wxf[1][0] = wx[nB * 2]; wxf[1][1] = wx[nB * 2 + 1];
    wbf[0] = wb[nA]; wbf[1] = wb[nB];
  }
  float cst[2][4];
#pragma unroll
  for (int nf = 0; nf < 2; ++nf) {
    int j = (n0 + nf * 16 + l15) >> 2;
#pragma unroll
    for (int r = 0; r < 4; ++r) {
      int b = bb0 + 4 * l4 + r;
      cst[nf][r] = (j < 510) ? cz0[(size_t)b * 512 + 2 + j] : 0.f;
    }
  }
  // stage input(0) into inp parity-region 0
  {
    const float* ip = rnn + (size_t)(bb0 + prow) * (TSTEPS * 64) + jc * 4;
    float4 inpv = *(const float4*)ip;
    s16x4 iv;
    iv[0] = (short)f2bf(inpv.x); iv[1] = (short)f2bf(inpv.y);
    iv[2] = (short)f2bf(inpv.z); iv[3] = (short)f2bf(inpv.w);
    *(s16x4*)(&u_sh[prow * URS + jc * 4]) = iv;
  }
  // h(0) init through the group's own exchange path: WG w writes row bb0+w of buf0
  {
    int b = bb0 + w;
    int j2 = tid * 2;
    u32 pv = 0;
    if (j2 < 510) {
      u16 lo = f2bf(z0[(size_t)b * 512 + 2 + j2]);
      u16 hi = (j2 + 1 < 510) ? f2bf(z0[(size_t)b * 512 + 3 + j2]) : (u16)0;
      pv = (u32)lo | ((u32)hi << 16);
    }
    hstore<M>((u32*)(hbuf + (size_t)b * 512) + tid, pv);
  }
  asm volatile("s_waitcnt vmcnt(0)" ::: "memory");
  if (l == 0) cnt_add1<M>(gc);        // 4 adds/WG -> 64/group gate for t=0
  __syncthreads();

  const int g = l & 3;
  const float sc_a = (g == 2) ? -2.88539008178f : -1.44269504089f;
  const float sc_m = (g == 2) ? 2.f : 1.f;
  const float sc_c = (g == 2) ? -1.f : 0.f;

  float tv_reg = 0.f;

  for (int t = 0; t <= TSTEPS; ++t) {
    const int cur = t & 1;
    // ---- per-wave poll: (count - base) >= 64*(t+1). RMW read -> never stale. ----
    {
      const u32 tgt = 64u * (u32)(t + 1);
      for (;;) {
        u32 c = 0;
        if (l == 0) c = cnt_read<M>(gc);
        c = (u32)__builtin_amdgcn_readfirstlane((int)c);
        if (c - cbase >= tgt) break;
      }
    }
    // ---- load h(t): L1 invalidate (mode1) then coalesced sc0 loads from the shared L2 ----
    if (M) {
      asm volatile("buffer_inv" ::: "memory");
      asm volatile("s_waitcnt vmcnt(0)" ::: "memory");
    }
    const u16* hb = hbuf + (size_t)cur * (256 * 512) + (size_t)bb0 * 512;
    u32x4 qa, qb, qc, qd;
    {
      const u16* hp = hb + (size_t)tid * 32;
      hload4<M>(hp, qa); hload4<M>(hp + 8, qb); hload4<M>(hp + 16, qc); hload4<M>(hp + 24, qd);
      asm volatile("s_waitcnt vmcnt(0)" ::: "memory");
      __builtin_amdgcn_sched_barrier(0);
    }
    u32 h32[16];
#pragma unroll
    for (int e = 0; e < 4; ++e) {
      h32[e] = qa[e]; h32[4 + e] = qb[e]; h32[8 + e] = qc[e]; h32[12 + e] = qd[e];
    }

    // dots: s[4] = h(t) . {alpha0,alpha1,hx0,hx1}, then jc-reduce
    float s0 = 0.f, s1 = 0.f, s2 = 0.f, s3 = 0.f;
#pragma unroll
    for (int q = 0; q < 4; ++q) {
#pragma unroll
      for (int p = 0; p < 4; ++p) {
        u32 h2 = h32[4 * q + p];
        s0 = dot2acc(h2, awr[0][q][p], s0);
        s1 = dot2acc(h2, awr[1][q][p], s1);
        s2 = dot2acc(h2, awr[2][q][p], s2);
        s3 = dot2acc(h2, awr[3][q][p], s3);
      }
    }
#pragma unroll
    for (int m = 1; m <= 8; m <<= 1) {
      s0 += __shfl_xor(s0, m, 64);
      s1 += __shfl_xor(s1, m, 64);
      s2 += __shfl_xor(s2, m, 64);
      s3 += __shfl_xor(s3, m, 64);
    }
    // stage h(t) into u_sh h-region (offset 128)
    {
      u16* ur = &u_sh[prow * URS + 128 + jc * 32];
      __builtin_memcpy(ur + 0, &qa, 16);
      __builtin_memcpy(ur + 8, &qb, 16);
      __builtin_memcpy(ur + 16, &qc, 16);
      __builtin_memcpy(ur + 24, &qd, 16);
    }
    if ((l & 15) == 0) {   // one lane per batch row: x recursion
      int row = prow;
      float xn0, xn1;
      if (t == 0) {
        xn0 = z0[(size_t)(bb0 + row) * 512 + 0];
        xn1 = z0[(size_t)(bb0 + row) * 512 + 1];
      } else {
        float x0p = xs_sh[cur ^ 1][row * 2 + 0], x1p = xs_sh[cur ^ 1][row * 2 + 1];
        float tv = tv_reg;
        float a0v = fsigm(s0 + ab0);
        float a1v = fsigm(s1 + ab1);
        float hx0 = s2 + ab2, hx1 = s3 + ab3;
        float xm0 = x0p + tv * (1.5f * x0p - 1.5f * x1p);
        float xm1 = x1p + tv * (0.6666666667f * x0p);
        xn0 = (1.f - a0v) * xm0 + a0v * hx0;
        xn1 = (1.f - a1v) * xm1 + a1v * hx1;
      }
      xs_sh[cur][row * 2 + 0] = xn0; xs_sh[cur][row * 2 + 1] = xn1;
    }
    __syncthreads();   // the only per-step barrier

    if (t == TSTEPS) {
      if (prow == w) {   // out[T-1] h + z_fin h from registers (h32 = h(T))
        float* ob = out + ((size_t)(bb0 + w) * TSTEPS + (TSTEPS - 1)) * 512 + 2 + jc * 32;
        float* zb = out + ZOFF + (size_t)(bb0 + w) * 512 + 2 + jc * 32;
#pragma unroll
        for (int p = 0; p < 16; ++p) {
          int col = jc * 32 + 2 * p;
          if (col < 510) {
            u32 h2 = h32[p];
            f32x2 fv;
            fv[0] = bf2f((u16)(h2 & 0xFFFFu));
            fv[1] = bf2f((u16)(h2 >> 16));
            NTS((f32x2*)(ob + 2 * p), fv);
            NTS((f32x2*)(zb + 2 * p), fv);
          }
        }
      }
      if ((l & 15) == 0 && w == prow) {
        int b = bb0 + prow;
        float xn0 = xs_sh[cur][prow * 2 + 0], xn1 = xs_sh[cur][prow * 2 + 1];
        float* ob = out + ((size_t)b * TSTEPS + (TSTEPS - 1)) * 512;
        NTS(ob + 0, xn0); NTS(ob + 1, xn1);
        NTS(&out[ZOFF + (size_t)b * 512 + 0], xn0);
        NTS(&out[ZOFF + (size_t)b * 512 + 1], xn1);
        NTS(&out[CZOFF + (size_t)b * 512 + 0], cz0[(size_t)b * 512 + 0]);
        NTS(&out[CZOFF + (size_t)b * 512 + 1], cz0[(size_t)b * 512 + 1]);
      }
      break;
    }

    // ---- GEMM: M16 x N32(per wave) x K576 ----
    f32x4 acc0 = {0.f, 0.f, 0.f, 0.f};
    f32x4 acc1 = {0.f, 0.f, 0.f, 0.f};
    {
      const u16* apF = &u_sh[l15 * URS + l4 * 8];
#pragma unroll
      for (int kf = 0; kf < 18; ++kf) {
        const u16* ap = (kf < 2) ? (apF + cur * 64 + kf * 32) : (apF + 64 + kf * 32);
        s16x8 a = *(const s16x8*)ap;
        acc0 = __builtin_amdgcn_mfma_f32_16x16x32_bf16(a, bfr[2 * kf + 0], acc0, 0, 0, 0);
        acc1 = __builtin_amdgcn_mfma_f32_16x16x32_bf16(a, bfr[2 * kf + 1], acc1, 0, 0, 0);
      }
    }
    // ---- epilogue ----
    float xr[4][2];
#pragma unroll
    for (int r = 0; r < 4; ++r) {
      xr[r][0] = xs_sh[cur][(4 * l4 + r) * 2 + 0];
      xr[r][1] = xs_sh[cur][(4 * l4 + r) * 2 + 1];
    }
    float myh0 = 0.f, myh1 = 0.f;
#pragma unroll
    for (int nf = 0; nf < 2; ++nf) {
      f32x4 av = nf ? acc1 : acc0;
#pragma unroll
      for (int r = 0; r < 4; ++r) {
        float pre = av[r] + wbf[nf] + xr[r][0] * wxf[nf][0] + xr[r][1] * wxf[nf][1];
        float y = __builtin_amdgcn_rcpf(1.f + __builtin_amdgcn_exp2f(sc_a * pre));
        float act = y * sc_m + sc_c;
        float vB = __shfl_xor(act, 1, 64);
        float vC = __shfl_xor(act, 2, 64);
        float vD = __shfl_xor(vB, 2, 64);
        float si = pick4(act, vB, vC, vD, g);
        float sf = pick4(act, vB, vC, vD, g ^ 1);
        float tg = pick4(act, vB, vC, vD, g ^ 2);
        float so = pick4(act, vB, vC, vD, g ^ 3);
        float cn = sf * cst[nf][r] + si * tg;
        cst[nf][r] = cn;
        float hn = so * ftanh(cn);
        if (g == r) { if (nf == 0) myh0 = hn; else myh1 = hn; }
      }
    }
    // ---- publish h(t+1) ----
    u16* hout = hbuf + (size_t)(cur ^ 1) * (256 * 512);
    {
      int row = 4 * l4 + g;
      u32 mine = (u32)f2bf(myh0) | ((u32)f2bf(myh1) << 16);
      u32 oth = (u32)__shfl_xor((int)mine, 4, 64);
      if (((l15 >> 2) & 1) == 0) {
        int j0 = (n0 >> 2) + (l15 >> 2);
        u32 v0 = (mine & 0xFFFFu) | ((oth & 0xFFFFu) << 16);
        u32 v1 = (mine >> 16) | (oth & 0xFFFF0000u);
        u32* hp = (u32*)(hout + (size_t)(bb0 + row) * 512);
        hstore<M>(hp + (j0 >> 1), v0);
        hstore<M>(hp + (j0 >> 1) + 2, v1);
      }
    }
    // ---- per-wave arrive: drain own publish stores, then count ----
    asm volatile("s_waitcnt vmcnt(0)" ::: "memory");
    if (l == 0) cnt_add1<M>(gc);
    // ---- shadow (post-arrive): out-writes from REGISTERS + staging + tau prefetch ----
    if (t >= 1 && prow == w) {
      float* ob = out + ((size_t)(bb0 + w) * TSTEPS + (t - 1)) * 512 + 2 + jc * 32;
#pragma unroll
      for (int p = 0; p < 16; ++p) {
        int col = jc * 32 + 2 * p;
        if (col < 510) {
          u32 h2 = h32[p];
          f32x2 fv;
          fv[0] = bf2f((u16)(h2 & 0xFFFFu));
          fv[1] = bf2f((u16)(h2 >> 16));
          NTS((f32x2*)(ob + 2 * p), fv);
        }
      }
    }
    if (t >= 1 && (l & 15) == 0 && w == prow) {
      float* ob = out + ((size_t)(bb0 + prow) * TSTEPS + (t - 1)) * 512;
      NTS(ob + 0, xs_sh[cur][prow * 2 + 0]); NTS(ob + 1, xs_sh[cur][prow * 2 + 1]);
    }
    if (t + 1 < TSTEPS) {
      const float* ip = rnn + (size_t)(bb0 + prow) * (TSTEPS * 64) + (size_t)(t + 1) * 64 + jc * 4;
      float4 inpv = *(const float4*)ip;
      s16x4 iv;
      iv[0] = (short)f2bf(inpv.x); iv[1] = (short)f2bf(inpv.y);
      iv[2] = (short)f2bf(inpv.z); iv[3] = (short)f2bf(inpv.w);
      *(s16x4*)(&u_sh[prow * URS + ((t + 1) & 1) * 64 + jc * 4]) = iv;
    }
    if ((l & 15) == 0) {
      tv_reg = tau[(size_t)(bb0 + prow) * TSTEPS + t];
    }
  }

  // ---- final cell state: cz_fin[:, 2:512] = c(T) ----
#pragma unroll
  for (int nf = 0; nf < 2; ++nf) {
    int j = (n0 + nf * 16 + l15) >> 2;
    if (j < 510) {
#pragma unroll
      for (int r = 0; r < 4; ++r) {
        if ((l & 3) == r) {
          NTS(&out[CZOFF + (size_t)(bb0 + 4 * l4 + r) * 512 + 2 + j], cst[nf][r]);
        }
      }
    }
  }
}

// ---------------- kernel: claim XCD slot, rendezvous, snapshot, dispatch body ----------------
extern "C" __global__ void __launch_bounds__(256, 1)
lstm_persist(const float* __restrict__ rnn, const float* __restrict__ tau,
             const float* __restrict__ z0, const float* __restrict__ cz0,
             const u16* __restrict__ wk, const float* __restrict__ wx, const float* __restrict__ wb,
             const u16* __restrict__ aw, const float* __restrict__ ab,
             u16* __restrict__ hbuf, u32* __restrict__ mall, u32* __restrict__ gcnt,
             float* __restrict__ out)
{
  __shared__ u16   u_sh[16 * URS];
  __shared__ float xs_sh[2][32];
  __shared__ u32   hdr[2];

  const int tid = threadIdx.x;
  const int bid = blockIdx.x;

  if (tid == 0) {
    u32 xcc;
    asm volatile("s_getreg_b32 %0, hwreg(20, 0, 32)" : "=s"(xcc));   // HW_REG_XCC_ID (measured m09)
    xcc &= 15u;
    u32 slot = __hip_atomic_fetch_add(&mall[16 * (1 + (int)xcc)], 1u,
                                      __ATOMIC_RELAXED, __HIP_MEMORY_SCOPE_AGENT);
    u32 addv = ((xcc >= 8u) || (slot >= 32u)) ? 0x10001u : 1u;   // ovf in high half
    // flush this XCD's stale dirty L2 lines (previous replay) BEFORE the rendezvous add:
    // all flushes complete before anyone snapshots or writes exchange lines.
    asm volatile("buffer_wbl2 sc1" ::: "memory");
    asm volatile("s_waitcnt vmcnt(0)" ::: "memory");
    __hip_atomic_fetch_add(&mall[0], addv, __ATOMIC_RELAXED, __HIP_MEMORY_SCOPE_AGENT);
    u32 rv;
    do {
      __builtin_amdgcn_s_sleep(2);
      rv = __hip_atomic_load(&mall[0], __ATOMIC_RELAXED, __HIP_MEMORY_SCOPE_AGENT);
    } while ((rv & 0xFFFFu) < 256u);
    int mode = (rv >> 16) ? 0 : 1;   // 1 = XCD-local L2 exchange, 0 = MALL fallback
    int grp, ww;
    if (mode) { grp = (int)xcc * 2 + (int)(slot >> 4); ww = (int)(slot & 15u); }
    else      { grp = bid & 15;                        ww = bid >> 4; }
    // snapshot the never-zeroed group counter (add-0 RMW), then group snap-barrier:
    // all members snap the same post-flush value before any real add happens.
    u32* gc = gcnt + grp * 16;
    u32 base = mode ? cnt_read<1>(gc) : cnt_read<0>(gc);
    __hip_atomic_fetch_add(&mall[16 * (17 + grp)], 1u, __ATOMIC_RELAXED, __HIP_MEMORY_SCOPE_AGENT);
    u32 sv;
    do {
      __builtin_amdgcn_s_sleep(2);
      sv = __hip_atomic_load(&mall[16 * (17 + grp)], __ATOMIC_RELAXED, __HIP_MEMORY_SCOPE_AGENT);
    } while (sv < 16u);
    hdr[0] = ((u32)mode << 16) | ((u32)grp << 8) | (u32)ww;
    hdr[1] = base;
  }
  __syncthreads();
  u32 h0v = hdr[0], cbase = hdr[1];
  int mode = (int)(h0v >> 16);
  int grp  = (int)((h0v >> 8) & 0xFFu);
  int ww   = (int)(h0v & 0xFFu);
  u32* gc = gcnt + grp * 16;

  if (mode)
    lstm_body<1>(rnn, tau, z0, cz0, wk, wx, wb, aw, ab, hbuf, gc, cbase, out, grp, ww, tid, u_sh, xs_sh);
  else
    lstm_body<0>(rnn, tau, z0, cz0, wk, wx, wb, aw, ab, hbuf, gc, cbase, out, grp, ww, tid, u_sh, xs_sh);
}

extern "C" void kernel_launch(void* const* d_in, const int* in_sizes, int n_in,
                              void* d_out, int out_size, void* d_ws, size_t ws_size,
                              hipStream_t stream) {
  const float* rnn     = (const float*)d_in[0];
  const float* tau     = (const float*)d_in[1];
  const float* z0      = (const float*)d_in[2];
  const float* cz0     = (const float*)d_in[3];
  const float* W_w     = (const float*)d_in[4];
  const float* W_b     = (const float*)d_in[5];
  const float* U_w     = (const float*)d_in[6];
  const float* alpha_w = (const float*)d_in[7];
  const float* alpha_b = (const float*)d_in[8];
  const float* hx_w    = (const float*)d_in[9];
  const float* hx_b    = (const float*)d_in[10];

  char* ws = (char*)d_ws;
  u32*      mall = (u32*)(ws + MALL_OFF);
  u32*      gcv  = (u32*)(ws + GC_OFF);
  u16*      hb   = (u16*)(ws + HB_OFF);
  u16*      wkv  = (u16*)(ws + WK_OFF);
  float*    wxv  = (float*)(ws + WX_OFF);
  float*    wbv  = (float*)(ws + WB_OFF);
  u16*      awv  = (u16*)(ws + AW_OFF);
  float*    abv  = (float*)(ws + AB_OFF);

  hipLaunchKernelGGL(prep_pack, dim3(2052), dim3(64), 0, stream,
                     W_w, W_b, U_w, alpha_w, alpha_b, hx_w, hx_b, wkv, wxv, wbv, awv, abv, mall);
  hipLaunchKernelGGL(lstm_persist, dim3(256), dim3(256), 0, stream,
                     rnn, tau, z0, cz0, wkv, wxv, wbv, awv, abv, hb, mall, gcv, (float*)d_out);
}

// Round 13
// 4757.919 us; speedup vs baseline: 1.7091x; 1.0898x over previous
//
#include <hip/hip_runtime.h>

typedef unsigned short u16;
typedef unsigned int u32;
typedef unsigned long long u64;
typedef __attribute__((ext_vector_type(8))) short s16x8;
typedef __attribute__((ext_vector_type(4))) short s16x4;
typedef __attribute__((ext_vector_type(4))) float f32x4;
typedef __attribute__((ext_vector_type(2))) float f32x2;
typedef __attribute__((ext_vector_type(4))) u32 u32x4;

#define TSTEPS 1024
#define URS    648                         // u_sh row stride u16: [inpA 64 | inpB 64 | h 512 | pad 8]
#define ZOFF   ((size_t)134217728)         // 256*1024*512
#define CZOFF  (ZOFF + 131072)             // + 256*512

// workspace layout (bytes)
#define MALL_OFF 0                         // 33 u32 lines x 64B: [0]=ready|ovf, [1..16]=claims, [17..32]=snapcnt
#define GC_OFF   4096                      // 16 group counters x 64B — NEVER zeroed (snapshot-based)
#define HB_OFF   8192                      // h double buffer: 2*256*512 u16
#define WK_OFF   (HB_OFF + 524288)         // packed weights 2048*576 u16
#define WX_OFF   (WK_OFF + 2359296)        // x-weights 2048*2 f32
#define WB_OFF   (WX_OFF + 16384)          // bias 2048 f32
#define AW_OFF   (WB_OFF + 8192)           // alpha/hx weights 4*512 u16
#define AB_OFF   (AW_OFF + 4096)           // alpha/hx biases 4 f32

__device__ __forceinline__ float bf2f(u16 h) { union { unsigned u; float f; } c; c.u = ((unsigned)h) << 16; return c.f; }
__device__ __forceinline__ u16 f2bf(float f) { union { float f; unsigned u; } c; c.f = f; unsigned u = c.u; return (u16)((u + 0x7FFFu + ((u >> 16) & 1u)) >> 16); }
__device__ __forceinline__ float fsigm(float x) { return __builtin_amdgcn_rcpf(1.f + __builtin_amdgcn_exp2f(-1.44269504089f * x)); }
__device__ __forceinline__ float ftanh(float x) { float t = __builtin_amdgcn_exp2f(2.88539008178f * x); return 1.f - 2.f * __builtin_amdgcn_rcpf(t + 1.f); }
__device__ __forceinline__ float pick4(float a, float b, float c, float d, int m) {
  return (m == 0) ? a : (m == 1) ? b : (m == 2) ? c : d;
}
#define NTS(p, v) __builtin_nontemporal_store((v), (p))

#if defined(__has_builtin)
#if __has_builtin(__builtin_amdgcn_fdot2_f32_bf16)
#define HAVE_DOT2 1
typedef __bf16 bf16x2 __attribute__((ext_vector_type(2)));
#endif
#endif

__device__ __forceinline__ float dot2acc(u32 h2, u32 a2, float acc) {
#ifdef HAVE_DOT2
  bf16x2 hv, av;
  __builtin_memcpy(&hv, &h2, 4);
  __builtin_memcpy(&av, &a2, 4);
  return __builtin_amdgcn_fdot2_f32_bf16(hv, av, acc, false);
#else
  acc += bf2f((u16)(h2 & 0xFFFFu)) * bf2f((u16)(a2 & 0xFFFFu));
  acc += bf2f((u16)(h2 >> 16)) * bf2f((u16)(a2 >> 16));
  return acc;
#endif
}

// ---- scope-templated exchange ops. M=1: XCD-local L2 (no sc1). M=0: MALL (sc1, r6-validated).
// ALL counter waits are atomic RMWs: atomics never complete in L1 -> no stale-L1 spin.
template<int M> __device__ __forceinline__ void cnt_add1(u32* p) {
  u32 one = 1u;
  if (M) asm volatile("global_atomic_add %0, %1, off" :: "v"(p), "v"(one) : "memory");
  else   asm volatile("global_atomic_add %0, %1, off sc1" :: "v"(p), "v"(one) : "memory");
}
template<int M> __device__ __forceinline__ u32 cnt_read(u32* p) {   // add-0, return old
  u32 r, z = 0;
  if (M) asm volatile("global_atomic_add %0, %1, %2, off sc0" : "=v"(r) : "v"(p), "v"(z) : "memory");
  else   asm volatile("global_atomic_add %0, %1, %2, off sc0 sc1" : "=v"(r) : "v"(p), "v"(z) : "memory");
  asm volatile("s_waitcnt vmcnt(0)" ::: "memory");
  __builtin_amdgcn_sched_barrier(0);
  return r;
}
template<int M> __device__ __forceinline__ void hstore(u32* p, u32 v) {
  if (M) asm volatile("global_store_dword %0, %1, off sc0" :: "v"(p), "v"(v) : "memory");
  else   asm volatile("global_store_dword %0, %1, off sc0 sc1" :: "v"(p), "v"(v) : "memory");
}
template<int M> __device__ __forceinline__ void hload4(const u16* p, u32x4& a) {
  if (M) asm volatile("global_load_dwordx4 %0, %1, off sc0" : "=v"(a) : "v"(p));
  else   asm volatile("global_load_dwordx4 %0, %1, off sc0 sc1" : "=v"(a) : "v"(p));
}

// ---------------- prep: pack weights; zero MALL sync lines (gcnt NOT zeroed) ----------------
__global__ void prep_pack(const float* __restrict__ W_w, const float* __restrict__ W_b,
                          const float* __restrict__ U_w, const float* __restrict__ alpha_w,
                          const float* __restrict__ alpha_b, const float* __restrict__ hx_w,
                          const float* __restrict__ hx_b,
                          u16* __restrict__ wk, float* __restrict__ wx, float* __restrict__ wb,
                          u16* __restrict__ aw, float* __restrict__ ab, u32* __restrict__ mall)
{
  int n = blockIdx.x;
  int tid = threadIdx.x;
  if (n < 2048) {
    int j = n >> 2, g = n & 3;
    bool real = (j < 510);
    int row = g * 510 + j;
    for (int k = tid; k < 576; k += 64) {
      float v = 0.f;
      if (real) {
        if (k < 64) v = W_w[row * 66 + 2 + k];
        else { int kk = k - 64; v = (kk < 510) ? U_w[row * 510 + kk] : 0.f; }
      }
      wk[(size_t)n * 576 + k] = f2bf(v);
    }
    if (tid == 0) {
      wx[n * 2 + 0] = real ? W_w[row * 66 + 0] : 0.f;
      wx[n * 2 + 1] = real ? W_w[row * 66 + 1] : 0.f;
      wb[n] = real ? W_b[row] : 0.f;
    }
    if (n == 0 && tid < 33)
      __hip_atomic_store(&mall[tid * 16], 0u, __ATOMIC_RELAXED, __HIP_MEMORY_SCOPE_AGENT);
  } else {
    int s = n - 2048; // 0,1: alpha rows; 2,3: hx rows
    for (int j = tid; j < 512; j += 64) {
      float v = 0.f;
      if (j < 510) v = (s < 2) ? alpha_w[s * 510 + j] : hx_w[(s - 2) * 510 + j];
      aw[s * 512 + j] = f2bf(v);
    }
    if (tid == 0) ab[s] = (s < 2) ? alpha_b[s] : hx_b[s - 2];
  }
}

// ---------------- persistent LSTM body (templated on exchange scope) ----------------
// Sync per step: per-wave arrive add (r12-validated) -> ONE poller per WG (wave0 lane0,
// RMW read) -> LDS-flag fanout to waves 1-3 (ds spin, zero fabric traffic). This cuts
// same-address L2 RMW traffic from ~1500/step (r12's 64-wave poll storm) to ~100/step.
template<int M>
__device__ __forceinline__ void lstm_body(
    const float* __restrict__ rnn, const float* __restrict__ tau,
    const float* __restrict__ z0, const float* __restrict__ cz0,
    const u16* __restrict__ wk, const float* __restrict__ wx, const float* __restrict__ wb,
    const u16* __restrict__ aw, const float* __restrict__ ab,
    u16* __restrict__ hbuf, u32* gc, u32 cbase, float* __restrict__ out,
    int grp, int w, int tid,
    u16* u_sh, float (*xs_sh)[32], u32* flg)
{
  const int bb0 = grp * 16;
  const int l   = tid & 63;
  const int l15 = l & 15, l4 = l >> 4;
  const int v   = tid >> 6;
  const int n0  = w * 128 + v * 32;
  const int prow = tid >> 4;
  const int jc   = tid & 15;

  // alpha/hx weights persistent in registers
  u32 awr[4][4][4];
  {
    const u32* awp = (const u32*)aw;
#pragma unroll
    for (int s = 0; s < 4; ++s)
#pragma unroll
      for (int q = 0; q < 4; ++q)
#pragma unroll
        for (int p = 0; p < 4; ++p)
          awr[s][q][p] = awp[(s * 512 + jc * 32 + q * 8) / 2 + p];
  }
  float ab0 = ab[0], ab1 = ab[1], ab2 = ab[2], ab3 = ab[3];

  // persistent B fragments
  s16x8 bfr[36];
  {
    const u16* wb0 = wk + (size_t)(n0 + l15) * 576 + l4 * 8;
#pragma unroll
    for (int kf = 0; kf < 18; ++kf) {
      bfr[2 * kf + 0] = *(const s16x8*)(wb0 + kf * 32);
      bfr[2 * kf + 1] = *(const s16x8*)(wb0 + 16 * 576 + kf * 32);
    }
  }
  float wxf[2][2], wbf[2];
  {
    int nA = n0 + l15, nB = nA + 16;
    wxf[0][0] = wx[nA * 2]; wxf[0][1] = wx[nA * 2 + 1];
    wxf[1][0] = wx[nB * 2]; wxf[1][1] = wx[nB * 2 + 1];
    wbf[0] = wb[nA]; wbf[1] = wb[nB];
  }
  float cst[2][4];
#pragma unroll
  for (int nf = 0; nf < 2; ++nf) {
    int j = (n0 + nf * 16 + l15) >> 2;
#pragma unroll
    for (int r = 0; r < 4; ++r) {
      int b = bb0 + 4 * l4 + r;
      cst[nf][r] = (j < 510) ? cz0[(size_t)b * 512 + 2 + j] : 0.f;
    }
  }
  // stage input(0) into inp parity-region 0; init LDS flag
  if (tid == 0) *flg = 0u;
  {
    const float* ip = rnn + (size_t)(bb0 + prow) * (TSTEPS * 64) + jc * 4;
    float4 inpv = *(const float4*)ip;
    s16x4 iv;
    iv[0] = (short)f2bf(inpv.x); iv[1] = (short)f2bf(inpv.y);
    iv[2] = (short)f2bf(inpv.z); iv[3] = (short)f2bf(inpv.w);
    *(s16x4*)(&u_sh[prow * URS + jc * 4]) = iv;
  }
  // h(0) init through the group's own exchange path: WG w writes row bb0+w of buf0
  {
    int b = bb0 + w;
    int j2 = tid * 2;
    u32 pv = 0;
    if (j2 < 510) {
      u16 lo = f2bf(z0[(size_t)b * 512 + 2 + j2]);
      u16 hi = (j2 + 1 < 510) ? f2bf(z0[(size_t)b * 512 + 3 + j2]) : (u16)0;
      pv = (u32)lo | ((u32)hi << 16);
    }
    hstore<M>((u32*)(hbuf + (size_t)b * 512) + tid, pv);
  }
  asm volatile("s_waitcnt vmcnt(0)" ::: "memory");
  if (l == 0) cnt_add1<M>(gc);        // 4 adds/WG -> 64/group gate for t=0
  __syncthreads();

  const int g = l & 3;
  const float sc_a = (g == 2) ? -2.88539008178f : -1.44269504089f;
  const float sc_m = (g == 2) ? 2.f : 1.f;
  const float sc_c = (g == 2) ? -1.f : 0.f;

  float tv_reg = 0.f;

  for (int t = 0; t <= TSTEPS; ++t) {
    const int cur = t & 1;
    // ---- gate for step t: ONE RMW poller per WG + LDS-flag fanout ----
    {
      const u32 tgt = 64u * (u32)(t + 1);
      if (v == 0) {
        if (l == 0) {
          while ((cnt_read<M>(gc) - cbase) < tgt) { }
          __hip_atomic_store(flg, tgt, __ATOMIC_RELAXED, __HIP_MEMORY_SCOPE_WORKGROUP);
        }
      } else {
        while (__hip_atomic_load(flg, __ATOMIC_RELAXED, __HIP_MEMORY_SCOPE_WORKGROUP) < tgt) { }
      }
      asm volatile("" ::: "memory");
    }
    // ---- load h(t): L1 invalidate (mode1) then coalesced sc0 loads from the shared L2 ----
    if (M) {
      asm volatile("buffer_inv" ::: "memory");
      asm volatile("s_waitcnt vmcnt(0)" ::: "memory");
    }
    const u16* hb = hbuf + (size_t)cur * (256 * 512) + (size_t)bb0 * 512;
    u32x4 qa, qb, qc, qd;
    {
      const u16* hp = hb + (size_t)tid * 32;
      hload4<M>(hp, qa); hload4<M>(hp + 8, qb); hload4<M>(hp + 16, qc); hload4<M>(hp + 24, qd);
      asm volatile("s_waitcnt vmcnt(0)" ::: "memory");
      __builtin_amdgcn_sched_barrier(0);
    }
    u32 h32[16];
#pragma unroll
    for (int e = 0; e < 4; ++e) {
      h32[e] = qa[e]; h32[4 + e] = qb[e]; h32[8 + e] = qc[e]; h32[12 + e] = qd[e];
    }

    // dots: s[4] = h(t) . {alpha0,alpha1,hx0,hx1}, then jc-reduce
    float s0 = 0.f, s1 = 0.f, s2 = 0.f, s3 = 0.f;
#pragma unroll
    for (int q = 0; q < 4; ++q) {
#pragma unroll
      for (int p = 0; p < 4; ++p) {
        u32 h2 = h32[4 * q + p];
        s0 = dot2acc(h2, awr[0][q][p], s0);
        s1 = dot2acc(h2, awr[1][q][p], s1);
        s2 = dot2acc(h2, awr[2][q][p], s2);
        s3 = dot2acc(h2, awr[3][q][p], s3);
      }
    }
#pragma unroll
    for (int m = 1; m <= 8; m <<= 1) {
      s0 += __shfl_xor(s0, m, 64);
      s1 += __shfl_xor(s1, m, 64);
      s2 += __shfl_xor(s2, m, 64);
      s3 += __shfl_xor(s3, m, 64);
    }
    // stage h(t) into u_sh h-region (offset 128)
    {
      u16* ur = &u_sh[prow * URS + 128 + jc * 32];
      __builtin_memcpy(ur + 0, &qa, 16);
      __builtin_memcpy(ur + 8, &qb, 16);
      __builtin_memcpy(ur + 16, &qc, 16);
      __builtin_memcpy(ur + 24, &qd, 16);
    }
    if ((l & 15) == 0) {   // one lane per batch row: x recursion
      int row = prow;
      float xn0, xn1;
      if (t == 0) {
        xn0 = z0[(size_t)(bb0 + row) * 512 + 0];
        xn1 = z0[(size_t)(bb0 + row) * 512 + 1];
      } else {
        float x0p = xs_sh[cur ^ 1][row * 2 + 0], x1p = xs_sh[cur ^ 1][row * 2 + 1];
        float tv = tv_reg;
        float a0v = fsigm(s0 + ab0);
        float a1v = fsigm(s1 + ab1);
        float hx0 = s2 + ab2, hx1 = s3 + ab3;
        float xm0 = x0p + tv * (1.5f * x0p - 1.5f * x1p);
        float xm1 = x1p + tv * (0.6666666667f * x0p);
        xn0 = (1.f - a0v) * xm0 + a0v * hx0;
        xn1 = (1.f - a1v) * xm1 + a1v * hx1;
      }
      xs_sh[cur][row * 2 + 0] = xn0; xs_sh[cur][row * 2 + 1] = xn1;
    }
    __syncthreads();   // the only per-step barrier

    if (t == TSTEPS) {
      if (prow == w) {   // out[T-1] h + z_fin h from registers (h32 = h(T))
        float* ob = out + ((size_t)(bb0 + w) * TSTEPS + (TSTEPS - 1)) * 512 + 2 + jc * 32;
        float* zb = out + ZOFF + (size_t)(bb0 + w) * 512 + 2 + jc * 32;
#pragma unroll
        for (int p = 0; p < 16; ++p) {
          int col = jc * 32 + 2 * p;
          if (col < 510) {
            u32 h2 = h32[p];
            f32x2 fv;
            fv[0] = bf2f((u16)(h2 & 0xFFFFu));
            fv[1] = bf2f((u16)(h2 >> 16));
            NTS((f32x2*)(ob + 2 * p), fv);
            NTS((f32x2*)(zb + 2 * p), fv);
          }
        }
      }
      if ((l & 15) == 0 && w == prow) {
        int b = bb0 + prow;
        float xn0 = xs_sh[cur][prow * 2 + 0], xn1 = xs_sh[cur][prow * 2 + 1];
        float* ob = out + ((size_t)b * TSTEPS + (TSTEPS - 1)) * 512;
        NTS(ob + 0, xn0); NTS(ob + 1, xn1);
        NTS(&out[ZOFF + (size_t)b * 512 + 0], xn0);
        NTS(&out[ZOFF + (size_t)b * 512 + 1], xn1);
        NTS(&out[CZOFF + (size_t)b * 512 + 0], cz0[(size_t)b * 512 + 0]);
        NTS(&out[CZOFF + (size_t)b * 512 + 1], cz0[(size_t)b * 512 + 1]);
      }
      break;
    }

    // ---- GEMM: M16 x N32(per wave) x K576 ----
    f32x4 acc0 = {0.f, 0.f, 0.f, 0.f};
    f32x4 acc1 = {0.f, 0.f, 0.f, 0.f};
    {
      const u16* apF = &u_sh[l15 * URS + l4 * 8];
#pragma unroll
      for (int kf = 0; kf < 18; ++kf) {
        const u16* ap = (kf < 2) ? (apF + cur * 64 + kf * 32) : (apF + 64 + kf * 32);
        s16x8 a = *(const s16x8*)ap;
        acc0 = __builtin_amdgcn_mfma_f32_16x16x32_bf16(a, bfr[2 * kf + 0], acc0, 0, 0, 0);
        acc1 = __builtin_amdgcn_mfma_f32_16x16x32_bf16(a, bfr[2 * kf + 1], acc1, 0, 0, 0);
      }
    }
    // ---- epilogue ----
    float xr[4][2];
#pragma unroll
    for (int r = 0; r < 4; ++r) {
      xr[r][0] = xs_sh[cur][(4 * l4 + r) * 2 + 0];
      xr[r][1] = xs_sh[cur][(4 * l4 + r) * 2 + 1];
    }
    float myh0 = 0.f, myh1 = 0.f;
#pragma unroll
    for (int nf = 0; nf < 2; ++nf) {
      f32x4 av = nf ? acc1 : acc0;
#pragma unroll
      for (int r = 0; r < 4; ++r) {
        float pre = av[r] + wbf[nf] + xr[r][0] * wxf[nf][0] + xr[r][1] * wxf[nf][1];
        float y = __builtin_amdgcn_rcpf(1.f + __builtin_amdgcn_exp2f(sc_a * pre));
        float act = y * sc_m + sc_c;
        float vB = __shfl_xor(act, 1, 64);
        float vC = __shfl_xor(act, 2, 64);
        float vD = __shfl_xor(vB, 2, 64);
        float si = pick4(act, vB, vC, vD, g);
        float sf = pick4(act, vB, vC, vD, g ^ 1);
        float tg = pick4(act, vB, vC, vD, g ^ 2);
        float so = pick4(act, vB, vC, vD, g ^ 3);
        float cn = sf * cst[nf][r] + si * tg;
        cst[nf][r] = cn;
        float hn = so * ftanh(cn);
        if (g == r) { if (nf == 0) myh0 = hn; else myh1 = hn; }
      }
    }
    // ---- publish h(t+1) ----
    u16* hout = hbuf + (size_t)(cur ^ 1) * (256 * 512);
    {
      int row = 4 * l4 + g;
      u32 mine = (u32)f2bf(myh0) | ((u32)f2bf(myh1) << 16);
      u32 oth = (u32)__shfl_xor((int)mine, 4, 64);
      if (((l15 >> 2) & 1) == 0) {
        int j0 = (n0 >> 2) + (l15 >> 2);
        u32 v0 = (mine & 0xFFFFu) | ((oth & 0xFFFFu) << 16);
        u32 v1 = (mine >> 16) | (oth & 0xFFFF0000u);
        u32* hp = (u32*)(hout + (size_t)(bb0 + row) * 512);
        hstore<M>(hp + (j0 >> 1), v0);
        hstore<M>(hp + (j0 >> 1) + 2, v1);
      }
    }
    // ---- per-wave arrive: drain own publish stores, then count ----
    asm volatile("s_waitcnt vmcnt(0)" ::: "memory");
    if (l == 0) cnt_add1<M>(gc);
    // ---- shadow (post-arrive): out-writes from REGISTERS + staging + tau prefetch ----
    if (t >= 1 && prow == w) {
      float* ob = out + ((size_t)(bb0 + w) * TSTEPS + (t - 1)) * 512 + 2 + jc * 32;
#pragma unroll
      for (int p = 0; p < 16; ++p) {
        int col = jc * 32 + 2 * p;
        if (col < 510) {
          u32 h2 = h32[p];
          f32x2 fv;
          fv[0] = bf2f((u16)(h2 & 0xFFFFu));
          fv[1] = bf2f((u16)(h2 >> 16));
          NTS((f32x2*)(ob + 2 * p), fv);
        }
      }
    }
    if (t >= 1 && (l & 15) == 0 && w == prow) {
      float* ob = out + ((size_t)(bb0 + prow) * TSTEPS + (t - 1)) * 512;
      NTS(ob + 0, xs_sh[cur][prow * 2 + 0]); NTS(ob + 1, xs_sh[cur][prow * 2 + 1]);
    }
    if (t + 1 < TSTEPS) {
      const float* ip = rnn + (size_t)(bb0 + prow) * (TSTEPS * 64) + (size_t)(t + 1) * 64 + jc * 4;
      float4 inpv = *(const float4*)ip;
      s16x4 iv;
      iv[0] = (short)f2bf(inpv.x); iv[1] = (short)f2bf(inpv.y);
      iv[2] = (short)f2bf(inpv.z); iv[3] = (short)f2bf(inpv.w);
      *(s16x4*)(&u_sh[prow * URS + ((t + 1) & 1) * 64 + jc * 4]) = iv;
    }
    if ((l & 15) == 0) {
      tv_reg = tau[(size_t)(bb0 + prow) * TSTEPS + t];
    }
  }

  // ---- final cell state: cz_fin[:, 2:512] = c(T) ----
#pragma unroll
  for (int nf = 0; nf < 2; ++nf) {
    int j = (n0 + nf * 16 + l15) >> 2;
    if (j < 510) {
#pragma unroll
      for (int r = 0; r < 4; ++r) {
        if ((l & 3) == r) {
          NTS(&out[CZOFF + (size_t)(bb0 + 4 * l4 + r) * 512 + 2 + j], cst[nf][r]);
        }
      }
    }
  }
}

// ---------------- kernel: claim XCD slot, rendezvous, snapshot, dispatch body ----------------
extern "C" __global__ void __launch_bounds__(256, 1)
lstm_persist(const float* __restrict__ rnn, const float* __restrict__ tau,
             const float* __restrict__ z0, const float* __restrict__ cz0,
             const u16* __restrict__ wk, const float* __restrict__ wx, const float* __restrict__ wb,
             const u16* __restrict__ aw, const float* __restrict__ ab,
             u16* __restrict__ hbuf, u32* __restrict__ mall, u32* __restrict__ gcnt,
             float* __restrict__ out)
{
  __shared__ u16   u_sh[16 * URS];
  __shared__ float xs_sh[2][32];
  __shared__ u32   hdr[2];
  __shared__ u32   flg;

  const int tid = threadIdx.x;
  const int bid = blockIdx.x;

  if (tid == 0) {
    u32 xcc;
    asm volatile("s_getreg_b32 %0, hwreg(20, 0, 32)" : "=s"(xcc));   // HW_REG_XCC_ID (measured m09)
    xcc &= 15u;
    u32 slot = __hip_atomic_fetch_add(&mall[16 * (1 + (int)xcc)], 1u,
                                      __ATOMIC_RELAXED, __HIP_MEMORY_SCOPE_AGENT);
    u32 addv = ((xcc >= 8u) || (slot >= 32u)) ? 0x10001u : 1u;   // ovf in high half
    asm volatile("buffer_wbl2 sc1" ::: "memory");
    asm volatile("s_waitcnt vmcnt(0)" ::: "memory");
    __hip_atomic_fetch_add(&mall[0], addv, __ATOMIC_RELAXED, __HIP_MEMORY_SCOPE_AGENT);
    u32 rv;
    do {
      __builtin_amdgcn_s_sleep(2);
      rv = __hip_atomic_load(&mall[0], __ATOMIC_RELAXED, __HIP_MEMORY_SCOPE_AGENT);
    } while ((rv & 0xFFFFu) < 256u);
    int mode = (rv >> 16) ? 0 : 1;   // 1 = XCD-local L2 exchange, 0 = MALL fallback
    int grp, ww;
    if (mode) { grp = (int)xcc * 2 + (int)(slot >> 4); ww = (int)(slot & 15u); }
    else      { grp = bid & 15;                        ww = bid >> 4; }
    u32* gc = gcnt + grp * 16;
    u32 base = mode ? cnt_read<1>(gc) : cnt_read<0>(gc);
    __hip_atomic_fetch_add(&mall[16 * (17 + grp)], 1u, __ATOMIC_RELAXED, __HIP_MEMORY_SCOPE_AGENT);
    u32 sv;
    do {
      __builtin_amdgcn_s_sleep(2);
      sv = __hip_atomic_load(&mall[16 * (17 + grp)], __ATOMIC_RELAXED, __HIP_MEMORY_SCOPE_AGENT);
    } while (sv < 16u);
    hdr[0] = ((u32)mode << 16) | ((u32)grp << 8) | (u32)ww;
    hdr[1] = base;
  }
  __syncthreads();
  u32 h0v = hdr[0], cbase = hdr[1];
  int mode = (int)(h0v >> 16);
  int grp  = (int)((h0v >> 8) & 0xFFu);
  int ww   = (int)(h0v & 0xFFu);
  u32* gc = gcnt + grp * 16;

  if (mode)
    lstm_body<1>(rnn, tau, z0, cz0, wk, wx, wb, aw, ab, hbuf, gc, cbase, out, grp, ww, tid, u_sh, xs_sh, &flg);
  else
    lstm_body<0>(rnn, tau, z0, cz0, wk, wx, wb, aw, ab, hbuf, gc, cbase, out, grp, ww, tid, u_sh, xs_sh, &flg);
}

extern "C" void kernel_launch(void* const* d_in, const int* in_sizes, int n_in,
                              void* d_out, int out_size, void* d_ws, size_t ws_size,
                              hipStream_t stream) {
  const float* rnn     = (const float*)d_in[0];
  const float* tau     = (const float*)d_in[1];
  const float* z0      = (const float*)d_in[2];
  const float* cz0     = (const float*)d_in[3];
  const float* W_w     = (const float*)d_in[4];
  const float* W_b     = (const float*)d_in[5];
  const float* U_w     = (const float*)d_in[6];
  const float* alpha_w = (const float*)d_in[7];
  const float* alpha_b = (const float*)d_in[8];
  const float* hx_w    = (const float*)d_in[9];
  const float* hx_b    = (const float*)d_in[10];

  char* ws = (char*)d_ws;
  u32*      mall = (u32*)(ws + MALL_OFF);
  u32*      gcv  = (u32*)(ws + GC_OFF);
  u16*      hb   = (u16*)(ws + HB_OFF);
  u16*      wkv  = (u16*)(ws + WK_OFF);
  float*    wxv  = (float*)(ws + WX_OFF);
  float*    wbv  = (float*)(ws + WB_OFF);
  u16*      awv  = (u16*)(ws + AW_OFF);
  float*    abv  = (float*)(ws + AB_OFF);

  hipLaunchKernelGGL(prep_pack, dim3(2052), dim3(64), 0, stream,
                     W_w, W_b, U_w, alpha_w, alpha_b, hx_w, hx_b, wkv, wxv, wbv, awv, abv, mall);
  hipLaunchKernelGGL(lstm_persist, dim3(256), dim3(256), 0, stream,
                     rnn, tau, z0, cz0, wkv, wxv, wbv, awv, abv, hb, mall, gcv, (float*)d_out);
}

// Round 14
// 4708.242 us; speedup vs baseline: 1.7271x; 1.0106x over previous
//
#include <hip/hip_runtime.h>

typedef unsigned short u16;
typedef unsigned int u32;
typedef unsigned long long u64;
typedef __attribute__((ext_vector_type(8))) short s16x8;
typedef __attribute__((ext_vector_type(4))) short s16x4;
typedef __attribute__((ext_vector_type(4))) float f32x4;
typedef __attribute__((ext_vector_type(2))) float f32x2;
typedef __attribute__((ext_vector_type(4))) u32 u32x4;

#define TSTEPS 1024
#define URS    648                         // u_sh row stride u16: [inpA 64 | inpB 64 | h 512 | pad 8]
#define ZOFF   ((size_t)134217728)         // 256*1024*512
#define CZOFF  (ZOFF + 131072)             // + 256*512

// workspace layout (bytes)
#define MALL_OFF 0                         // 33 u32 lines x 64B: [0]=ready|ovf, [1..16]=claims, [17..32]=snapcnt
#define GC_OFF   4096                      // 16 group counters x 64B — NEVER zeroed (snapshot-based)
#define HB_OFF   8192                      // h double buffer: 2*256*512 u16
#define WK_OFF   (HB_OFF + 524288)         // packed weights 2048*576 u16
#define WX_OFF   (WK_OFF + 2359296)        // x-weights 2048*2 f32
#define WB_OFF   (WX_OFF + 16384)          // bias 2048 f32
#define AW_OFF   (WB_OFF + 8192)           // alpha/hx weights 4*512 u16
#define AB_OFF   (AW_OFF + 4096)           // alpha/hx biases 4 f32

__device__ __forceinline__ float bf2f(u16 h) { union { unsigned u; float f; } c; c.u = ((unsigned)h) << 16; return c.f; }
__device__ __forceinline__ u16 f2bf(float f) { union { float f; unsigned u; } c; c.f = f; unsigned u = c.u; return (u16)((u + 0x7FFFu + ((u >> 16) & 1u)) >> 16); }
__device__ __forceinline__ float fsigm(float x) { return __builtin_amdgcn_rcpf(1.f + __builtin_amdgcn_exp2f(-1.44269504089f * x)); }
__device__ __forceinline__ float ftanh(float x) { float t = __builtin_amdgcn_exp2f(2.88539008178f * x); return 1.f - 2.f * __builtin_amdgcn_rcpf(t + 1.f); }
__device__ __forceinline__ float pick4(float a, float b, float c, float d, int m) {
  return (m == 0) ? a : (m == 1) ? b : (m == 2) ? c : d;
}
#define NTS(p, v) __builtin_nontemporal_store((v), (p))
#define NTL(p) __builtin_nontemporal_load(p)

#if defined(__has_builtin)
#if __has_builtin(__builtin_amdgcn_fdot2_f32_bf16)
#define HAVE_DOT2 1
typedef __bf16 bf16x2 __attribute__((ext_vector_type(2)));
#endif
#endif

__device__ __forceinline__ float dot2acc(u32 h2, u32 a2, float acc) {
#ifdef HAVE_DOT2
  bf16x2 hv, av;
  __builtin_memcpy(&hv, &h2, 4);
  __builtin_memcpy(&av, &a2, 4);
  return __builtin_amdgcn_fdot2_f32_bf16(hv, av, acc, false);
#else
  acc += bf2f((u16)(h2 & 0xFFFFu)) * bf2f((u16)(a2 & 0xFFFFu));
  acc += bf2f((u16)(h2 >> 16)) * bf2f((u16)(a2 >> 16));
  return acc;
#endif
}

// ---- scope-templated exchange ops. M=1: XCD-local L2 (no sc1). M=0: MALL (sc1, r6-validated).
// ALL counter waits are atomic RMWs: atomics never complete in L1 -> no stale-L1 spin.
template<int M> __device__ __forceinline__ void cnt_add1(u32* p) {
  u32 one = 1u;
  if (M) asm volatile("global_atomic_add %0, %1, off" :: "v"(p), "v"(one) : "memory");
  else   asm volatile("global_atomic_add %0, %1, off sc1" :: "v"(p), "v"(one) : "memory");
}
template<int M> __device__ __forceinline__ u32 cnt_read(u32* p) {   // add-0, return old
  u32 r, z = 0;
  if (M) asm volatile("global_atomic_add %0, %1, %2, off sc0" : "=v"(r) : "v"(p), "v"(z) : "memory");
  else   asm volatile("global_atomic_add %0, %1, %2, off sc0 sc1" : "=v"(r) : "v"(p), "v"(z) : "memory");
  asm volatile("s_waitcnt vmcnt(0)" ::: "memory");
  __builtin_amdgcn_sched_barrier(0);
  return r;
}
template<int M> __device__ __forceinline__ void hstore(u32* p, u32 v) {
  if (M) asm volatile("global_store_dword %0, %1, off sc0" :: "v"(p), "v"(v) : "memory");
  else   asm volatile("global_store_dword %0, %1, off sc0 sc1" :: "v"(p), "v"(v) : "memory");
}
template<int M> __device__ __forceinline__ void hload4(const u16* p, u32x4& a) {
  if (M) asm volatile("global_load_dwordx4 %0, %1, off sc0" : "=v"(a) : "v"(p));
  else   asm volatile("global_load_dwordx4 %0, %1, off sc0 sc1" : "=v"(a) : "v"(p));
}

// ---------------- prep: pack weights; zero MALL sync lines (gcnt NOT zeroed) ----------------
__global__ void prep_pack(const float* __restrict__ W_w, const float* __restrict__ W_b,
                          const float* __restrict__ U_w, const float* __restrict__ alpha_w,
                          const float* __restrict__ alpha_b, const float* __restrict__ hx_w,
                          const float* __restrict__ hx_b,
                          u16* __restrict__ wk, float* __restrict__ wx, float* __restrict__ wb,
                          u16* __restrict__ aw, float* __restrict__ ab, u32* __restrict__ mall)
{
  int n = blockIdx.x;
  int tid = threadIdx.x;
  if (n < 2048) {
    int j = n >> 2, g = n & 3;
    bool real = (j < 510);
    int row = g * 510 + j;
    for (int k = tid; k < 576; k += 64) {
      float v = 0.f;
      if (real) {
        if (k < 64) v = W_w[row * 66 + 2 + k];
        else { int kk = k - 64; v = (kk < 510) ? U_w[row * 510 + kk] : 0.f; }
      }
      wk[(size_t)n * 576 + k] = f2bf(v);
    }
    if (tid == 0) {
      wx[n * 2 + 0] = real ? W_w[row * 66 + 0] : 0.f;
      wx[n * 2 + 1] = real ? W_w[row * 66 + 1] : 0.f;
      wb[n] = real ? W_b[row] : 0.f;
    }
    if (n == 0 && tid < 33)
      __hip_atomic_store(&mall[tid * 16], 0u, __ATOMIC_RELAXED, __HIP_MEMORY_SCOPE_AGENT);
  } else {
    int s = n - 2048; // 0,1: alpha rows; 2,3: hx rows
    for (int j = tid; j < 512; j += 64) {
      float v = 0.f;
      if (j < 510) v = (s < 2) ? alpha_w[s * 510 + j] : hx_w[(s - 2) * 510 + j];
      aw[s * 512 + j] = f2bf(v);
    }
    if (tid == 0) ab[s] = (s < 2) ? alpha_b[s] : hx_b[s - 2];
  }
}

// ---------------- persistent LSTM body (templated on exchange scope) ----------------
// r14 changes vs r13 (protocol semantics unchanged):
//  - rnn/tau loads are NONTEMPORAL: they no longer evict the h exchange lines from the
//    XCD L2 (r13's WRITE_SIZE excess = dirty-h writebacks; re-loads cost ~900cy + gate
//    amplifies the slowest WG's miss).
//  - arrive consolidated: __syncthreads (drains every wave's publishes) + ONE tid0 add
//    (16 adds/group-step instead of 64 serialized same-line RMWs).
//  - buffer_inv moved OFF the critical path into the shadow zone.
template<int M>
__device__ __forceinline__ void lstm_body(
    const float* __restrict__ rnn, const float* __restrict__ tau,
    const float* __restrict__ z0, const float* __restrict__ cz0,
    const u16* __restrict__ wk, const float* __restrict__ wx, const float* __restrict__ wb,
    const u16* __restrict__ aw, const float* __restrict__ ab,
    u16* __restrict__ hbuf, u32* gc, u32 cbase, float* __restrict__ out,
    int grp, int w, int tid,
    u16* u_sh, float (*xs_sh)[32], u32* flg)
{
  const int bb0 = grp * 16;
  const int l   = tid & 63;
  const int l15 = l & 15, l4 = l >> 4;
  const int v   = tid >> 6;
  const int n0  = w * 128 + v * 32;
  const int prow = tid >> 4;
  const int jc   = tid & 15;

  // alpha/hx weights persistent in registers
  u32 awr[4][4][4];
  {
    const u32* awp = (const u32*)aw;
#pragma unroll
    for (int s = 0; s < 4; ++s)
#pragma unroll
      for (int q = 0; q < 4; ++q)
#pragma unroll
        for (int p = 0; p < 4; ++p)
          awr[s][q][p] = awp[(s * 512 + jc * 32 + q * 8) / 2 + p];
  }
  float ab0 = ab[0], ab1 = ab[1], ab2 = ab[2], ab3 = ab[3];

  // persistent B fragments
  s16x8 bfr[36];
  {
    const u16* wb0 = wk + (size_t)(n0 + l15) * 576 + l4 * 8;
#pragma unroll
    for (int kf = 0; kf < 18; ++kf) {
      bfr[2 * kf + 0] = *(const s16x8*)(wb0 + kf * 32);
      bfr[2 * kf + 1] = *(const s16x8*)(wb0 + 16 * 576 + kf * 32);
    }
  }
  float wxf[2][2], wbf[2];
  {
    int nA = n0 + l15, nB = nA + 16;
    wxf[0][0] = wx[nA * 2]; wxf[0][1] = wx[nA * 2 + 1];
    wxf[1][0] = wx[nB * 2]; wxf[1][1] = wx[nB * 2 + 1];
    wbf[0] = wb[nA]; wbf[1] = wb[nB];
  }
  float cst[2][4];
#pragma unroll
  for (int nf = 0; nf < 2; ++nf) {
    int j = (n0 + nf * 16 + l15) >> 2;
#pragma unroll
    for (int r = 0; r < 4; ++r) {
      int b = bb0 + 4 * l4 + r;
      cst[nf][r] = (j < 510) ? cz0[(size_t)b * 512 + 2 + j] : 0.f;
    }
  }
  // stage input(0) into inp parity-region 0; init LDS flag
  if (tid == 0) *flg = 0u;
  {
    const f32x4 inpv = NTL((const f32x4*)(rnn + (size_t)(bb0 + prow) * (TSTEPS * 64) + jc * 4));
    s16x4 iv;
    iv[0] = (short)f2bf(inpv[0]); iv[1] = (short)f2bf(inpv[1]);
    iv[2] = (short)f2bf(inpv[2]); iv[3] = (short)f2bf(inpv[3]);
    *(s16x4*)(&u_sh[prow * URS + jc * 4]) = iv;
  }
  // h(0) init through the group's own exchange path: WG w writes row bb0+w of buf0
  {
    int b = bb0 + w;
    int j2 = tid * 2;
    u32 pv = 0;
    if (j2 < 510) {
      u16 lo = f2bf(z0[(size_t)b * 512 + 2 + j2]);
      u16 hi = (j2 + 1 < 510) ? f2bf(z0[(size_t)b * 512 + 3 + j2]) : (u16)0;
      pv = (u32)lo | ((u32)hi << 16);
    }
    hstore<M>((u32*)(hbuf + (size_t)b * 512) + tid, pv);
  }
  __syncthreads();                     // drains every wave's h0 publishes (vmcnt 0)
  if (tid == 0) cnt_add1<M>(gc);       // ONE arrive per WG -> 16/group gate for t=0
  if (M) {
    asm volatile("buffer_inv" ::: "memory");   // clean L1 before first h-load
    asm volatile("s_waitcnt vmcnt(0)" ::: "memory");
  }

  const int g = l & 3;
  const float sc_a = (g == 2) ? -2.88539008178f : -1.44269504089f;
  const float sc_m = (g == 2) ? 2.f : 1.f;
  const float sc_c = (g == 2) ? -1.f : 0.f;

  float tv_reg = 0.f;

  for (int t = 0; t <= TSTEPS; ++t) {
    const int cur = t & 1;
    // ---- gate for step t: ONE RMW poller per WG + LDS-flag fanout ----
    {
      const u32 tgt = 16u * (u32)(t + 1);
      if (v == 0) {
        if (l == 0) {
          while ((cnt_read<M>(gc) - cbase) < tgt) { }
          __hip_atomic_store(flg, tgt, __ATOMIC_RELAXED, __HIP_MEMORY_SCOPE_WORKGROUP);
        }
      } else {
        while (__hip_atomic_load(flg, __ATOMIC_RELAXED, __HIP_MEMORY_SCOPE_WORKGROUP) < tgt) { }
      }
      asm volatile("" ::: "memory");
    }
    // ---- load h(t): coalesced sc0 loads from the shared L2 (L1 cleaned in shadow) ----
    const u16* hb = hbuf + (size_t)cur * (256 * 512) + (size_t)bb0 * 512;
    u32x4 qa, qb, qc, qd;
    {
      const u16* hp = hb + (size_t)tid * 32;
      hload4<M>(hp, qa); hload4<M>(hp + 8, qb); hload4<M>(hp + 16, qc); hload4<M>(hp + 24, qd);
      asm volatile("s_waitcnt vmcnt(0)" ::: "memory");
      __builtin_amdgcn_sched_barrier(0);
    }
    u32 h32[16];
#pragma unroll
    for (int e = 0; e < 4; ++e) {
      h32[e] = qa[e]; h32[4 + e] = qb[e]; h32[8 + e] = qc[e]; h32[12 + e] = qd[e];
    }

    // dots: s[4] = h(t) . {alpha0,alpha1,hx0,hx1}, then jc-reduce
    float s0 = 0.f, s1 = 0.f, s2 = 0.f, s3 = 0.f;
#pragma unroll
    for (int q = 0; q < 4; ++q) {
#pragma unroll
      for (int p = 0; p < 4; ++p) {
        u32 h2 = h32[4 * q + p];
        s0 = dot2acc(h2, awr[0][q][p], s0);
        s1 = dot2acc(h2, awr[1][q][p], s1);
        s2 = dot2acc(h2, awr[2][q][p], s2);
        s3 = dot2acc(h2, awr[3][q][p], s3);
      }
    }
#pragma unroll
    for (int m = 1; m <= 8; m <<= 1) {
      s0 += __shfl_xor(s0, m, 64);
      s1 += __shfl_xor(s1, m, 64);
      s2 += __shfl_xor(s2, m, 64);
      s3 += __shfl_xor(s3, m, 64);
    }
    // stage h(t) into u_sh h-region (offset 128)
    {
      u16* ur = &u_sh[prow * URS + 128 + jc * 32];
      __builtin_memcpy(ur + 0, &qa, 16);
      __builtin_memcpy(ur + 8, &qb, 16);
      __builtin_memcpy(ur + 16, &qc, 16);
      __builtin_memcpy(ur + 24, &qd, 16);
    }
    if ((l & 15) == 0) {   // one lane per batch row: x recursion
      int row = prow;
      float xn0, xn1;
      if (t == 0) {
        xn0 = z0[(size_t)(bb0 + row) * 512 + 0];
        xn1 = z0[(size_t)(bb0 + row) * 512 + 1];
      } else {
        float x0p = xs_sh[cur ^ 1][row * 2 + 0], x1p = xs_sh[cur ^ 1][row * 2 + 1];
        float tv = tv_reg;
        float a0v = fsigm(s0 + ab0);
        float a1v = fsigm(s1 + ab1);
        float hx0 = s2 + ab2, hx1 = s3 + ab3;
        float xm0 = x0p + tv * (1.5f * x0p - 1.5f * x1p);
        float xm1 = x1p + tv * (0.6666666667f * x0p);
        xn0 = (1.f - a0v) * xm0 + a0v * hx0;
        xn1 = (1.f - a1v) * xm1 + a1v * hx1;
      }
      xs_sh[cur][row * 2 + 0] = xn0; xs_sh[cur][row * 2 + 1] = xn1;
    }
    __syncthreads();   // mid-step barrier: u_sh/xs_sh[cur] ready for all waves

    if (t == TSTEPS) {
      if (prow == w) {   // out[T-1] h + z_fin h from registers (h32 = h(T))
        float* ob = out + ((size_t)(bb0 + w) * TSTEPS + (TSTEPS - 1)) * 512 + 2 + jc * 32;
        float* zb = out + ZOFF + (size_t)(bb0 + w) * 512 + 2 + jc * 32;
#pragma unroll
        for (int p = 0; p < 16; ++p) {
          int col = jc * 32 + 2 * p;
          if (col < 510) {
            u32 h2 = h32[p];
            f32x2 fv;
            fv[0] = bf2f((u16)(h2 & 0xFFFFu));
            fv[1] = bf2f((u16)(h2 >> 16));
            NTS((f32x2*)(ob + 2 * p), fv);
            NTS((f32x2*)(zb + 2 * p), fv);
          }
        }
      }
      if ((l & 15) == 0 && w == prow) {
        int b = bb0 + prow;
        float xn0 = xs_sh[cur][prow * 2 + 0], xn1 = xs_sh[cur][prow * 2 + 1];
        float* ob = out + ((size_t)b * TSTEPS + (TSTEPS - 1)) * 512;
        NTS(ob + 0, xn0); NTS(ob + 1, xn1);
        NTS(&out[ZOFF + (size_t)b * 512 + 0], xn0);
        NTS(&out[ZOFF + (size_t)b * 512 + 1], xn1);
        NTS(&out[CZOFF + (size_t)b * 512 + 0], cz0[(size_t)b * 512 + 0]);
        NTS(&out[CZOFF + (size_t)b * 512 + 1], cz0[(size_t)b * 512 + 1]);
      }
      break;
    }

    // ---- GEMM: M16 x N32(per wave) x K576 ----
    f32x4 acc0 = {0.f, 0.f, 0.f, 0.f};
    f32x4 acc1 = {0.f, 0.f, 0.f, 0.f};
    {
      const u16* apF = &u_sh[l15 * URS + l4 * 8];
#pragma unroll
      for (int kf = 0; kf < 18; ++kf) {
        const u16* ap = (kf < 2) ? (apF + cur * 64 + kf * 32) : (apF + 64 + kf * 32);
        s16x8 a = *(const s16x8*)ap;
        acc0 = __builtin_amdgcn_mfma_f32_16x16x32_bf16(a, bfr[2 * kf + 0], acc0, 0, 0, 0);
        acc1 = __builtin_amdgcn_mfma_f32_16x16x32_bf16(a, bfr[2 * kf + 1], acc1, 0, 0, 0);
      }
    }
    // ---- epilogue ----
    float xr[4][2];
#pragma unroll
    for (int r = 0; r < 4; ++r) {
      xr[r][0] = xs_sh[cur][(4 * l4 + r) * 2 + 0];
      xr[r][1] = xs_sh[cur][(4 * l4 + r) * 2 + 1];
    }
    float myh0 = 0.f, myh1 = 0.f;
#pragma unroll
    for (int nf = 0; nf < 2; ++nf) {
      f32x4 av = nf ? acc1 : acc0;
#pragma unroll
      for (int r = 0; r < 4; ++r) {
        float pre = av[r] + wbf[nf] + xr[r][0] * wxf[nf][0] + xr[r][1] * wxf[nf][1];
        float y = __builtin_amdgcn_rcpf(1.f + __builtin_amdgcn_exp2f(sc_a * pre));
        float act = y * sc_m + sc_c;
        float vB = __shfl_xor(act, 1, 64);
        float vC = __shfl_xor(act, 2, 64);
        float vD = __shfl_xor(vB, 2, 64);
        float si = pick4(act, vB, vC, vD, g);
        float sf = pick4(act, vB, vC, vD, g ^ 1);
        float tg = pick4(act, vB, vC, vD, g ^ 2);
        float so = pick4(act, vB, vC, vD, g ^ 3);
        float cn = sf * cst[nf][r] + si * tg;
        cst[nf][r] = cn;
        float hn = so * ftanh(cn);
        if (g == r) { if (nf == 0) myh0 = hn; else myh1 = hn; }
      }
    }
    // ---- publish h(t+1) ----
    u16* hout = hbuf + (size_t)(cur ^ 1) * (256 * 512);
    {
      int row = 4 * l4 + g;
      u32 mine = (u32)f2bf(myh0) | ((u32)f2bf(myh1) << 16);
      u32 oth = (u32)__shfl_xor((int)mine, 4, 64);
      if (((l15 >> 2) & 1) == 0) {
        int j0 = (n0 >> 2) + (l15 >> 2);
        u32 v0 = (mine & 0xFFFFu) | ((oth & 0xFFFFu) << 16);
        u32 v1 = (mine >> 16) | (oth & 0xFFFF0000u);
        u32* hp = (u32*)(hout + (size_t)(bb0 + row) * 512);
        hstore<M>(hp + (j0 >> 1), v0);
        hstore<M>(hp + (j0 >> 1) + 2, v1);
      }
    }
    // ---- arrive: barrier drains every wave's publishes, then ONE add per WG ----
    __syncthreads();
    if (tid == 0) cnt_add1<M>(gc);
    // ---- shadow (post-arrive): out-writes from REGISTERS + NT staging + tau + L1 inv ----
    if (t >= 1 && prow == w) {
      float* ob = out + ((size_t)(bb0 + w) * TSTEPS + (t - 1)) * 512 + 2 + jc * 32;
#pragma unroll
      for (int p = 0; p < 16; ++p) {
        int col = jc * 32 + 2 * p;
        if (col < 510) {
          u32 h2 = h32[p];
          f32x2 fv;
          fv[0] = bf2f((u16)(h2 & 0xFFFFu));
          fv[1] = bf2f((u16)(h2 >> 16));
          NTS((f32x2*)(ob + 2 * p), fv);
        }
      }
    }
    if (t >= 1 && (l & 15) == 0 && w == prow) {
      float* ob = out + ((size_t)(bb0 + prow) * TSTEPS + (t - 1)) * 512;
      NTS(ob + 0, xs_sh[cur][prow * 2 + 0]); NTS(ob + 1, xs_sh[cur][prow * 2 + 1]);
    }
    if (t + 1 < TSTEPS) {
      // NONTEMPORAL: rnn is read-once streaming; keep it out of the L2 so it can't
      // evict the h exchange lines (r13: dirty-h writebacks + HBM re-load jitter).
      const f32x4 inpv = NTL((const f32x4*)(rnn + (size_t)(bb0 + prow) * (TSTEPS * 64)
                                            + (size_t)(t + 1) * 64 + jc * 4));
      s16x4 iv;
      iv[0] = (short)f2bf(inpv[0]); iv[1] = (short)f2bf(inpv[1]);
      iv[2] = (short)f2bf(inpv[2]); iv[3] = (short)f2bf(inpv[3]);
      *(s16x4*)(&u_sh[prow * URS + ((t + 1) & 1) * 64 + jc * 4]) = iv;
    }
    if ((l & 15) == 0) {
      tv_reg = NTL(&tau[(size_t)(bb0 + prow) * TSTEPS + t]);
    }
    if (M) {
      asm volatile("buffer_inv" ::: "memory");          // off critical path: clean L1
      asm volatile("s_waitcnt vmcnt(0)" ::: "memory");  // before next step's h-load
    }
  }

  // ---- final cell state: cz_fin[:, 2:512] = c(T) ----
#pragma unroll
  for (int nf = 0; nf < 2; ++nf) {
    int j = (n0 + nf * 16 + l15) >> 2;
    if (j < 510) {
#pragma unroll
      for (int r = 0; r < 4; ++r) {
        if ((l & 3) == r) {
          NTS(&out[CZOFF + (size_t)(bb0 + 4 * l4 + r) * 512 + 2 + j], cst[nf][r]);
        }
      }
    }
  }
}

// ---------------- kernel: claim XCD slot, rendezvous, snapshot, dispatch body ----------------
extern "C" __global__ void __launch_bounds__(256, 1)
lstm_persist(const float* __restrict__ rnn, const float* __restrict__ tau,
             const float* __restrict__ z0, const float* __restrict__ cz0,
             const u16* __restrict__ wk, const float* __restrict__ wx, const float* __restrict__ wb,
             const u16* __restrict__ aw, const float* __restrict__ ab,
             u16* __restrict__ hbuf, u32* __restrict__ mall, u32* __restrict__ gcnt,
             float* __restrict__ out)
{
  __shared__ u16   u_sh[16 * URS];
  __shared__ float xs_sh[2][32];
  __shared__ u32   hdr[2];
  __shared__ u32   flg;

  const int tid = threadIdx.x;
  const int bid = blockIdx.x;

  if (tid == 0) {
    u32 xcc;
    asm volatile("s_getreg_b32 %0, hwreg(20, 0, 32)" : "=s"(xcc));   // HW_REG_XCC_ID (measured m09)
    xcc &= 15u;
    u32 slot = __hip_atomic_fetch_add(&mall[16 * (1 + (int)xcc)], 1u,
                                      __ATOMIC_RELAXED, __HIP_MEMORY_SCOPE_AGENT);
    u32 addv = ((xcc >= 8u) || (slot >= 32u)) ? 0x10001u : 1u;   // ovf in high half
    asm volatile("buffer_wbl2 sc1" ::: "memory");
    asm volatile("s_waitcnt vmcnt(0)" ::: "memory");
    __hip_atomic_fetch_add(&mall[0], addv, __ATOMIC_RELAXED, __HIP_MEMORY_SCOPE_AGENT);
    u32 rv;
    do {
      __builtin_amdgcn_s_sleep(2);
      rv = __hip_atomic_load(&mall[0], __ATOMIC_RELAXED, __HIP_MEMORY_SCOPE_AGENT);
    } while ((rv & 0xFFFFu) < 256u);
    int mode = (rv >> 16) ? 0 : 1;   // 1 = XCD-local L2 exchange, 0 = MALL fallback
    int grp, ww;
    if (mode) { grp = (int)xcc * 2 + (int)(slot >> 4); ww = (int)(slot & 15u); }
    else      { grp = bid & 15;                        ww = bid >> 4; }
    u32* gc = gcnt + grp * 16;
    u32 base = mode ? cnt_read<1>(gc) : cnt_read<0>(gc);
    __hip_atomic_fetch_add(&mall[16 * (17 + grp)], 1u, __ATOMIC_RELAXED, __HIP_MEMORY_SCOPE_AGENT);
    u32 sv;
    do {
      __builtin_amdgcn_s_sleep(2);
      sv = __hip_atomic_load(&mall[16 * (17 + grp)], __ATOMIC_RELAXED, __HIP_MEMORY_SCOPE_AGENT);
    } while (sv < 16u);
    hdr[0] = ((u32)mode << 16) | ((u32)grp << 8) | (u32)ww;
    hdr[1] = base;
  }
  __syncthreads();
  u32 h0v = hdr[0], cbase = hdr[1];
  int mode = (int)(h0v >> 16);
  int grp  = (int)((h0v >> 8) & 0xFFu);
  int ww   = (int)(h0v & 0xFFu);
  u32* gc = gcnt + grp * 16;

  if (mode)
    lstm_body<1>(rnn, tau, z0, cz0, wk, wx, wb, aw, ab, hbuf, gc, cbase, out, grp, ww, tid, u_sh, xs_sh, &flg);
  else
    lstm_body<0>(rnn, tau, z0, cz0, wk, wx, wb, aw, ab, hbuf, gc, cbase, out, grp, ww, tid, u_sh, xs_sh, &flg);
}

extern "C" void kernel_launch(void* const* d_in, const int* in_sizes, int n_in,
                              void* d_out, int out_size, void* d_ws, size_t ws_size,
                              hipStream_t stream) {
  const float* rnn     = (const float*)d_in[0];
  const float* tau     = (const float*)d_in[1];
  const float* z0      = (const float*)d_in[2];
  const float* cz0     = (const float*)d_in[3];
  const float* W_w     = (const float*)d_in[4];
  const float* W_b     = (const float*)d_in[5];
  const float* U_w     = (const float*)d_in[6];
  const float* alpha_w = (const float*)d_in[7];
  const float* alpha_b = (const float*)d_in[8];
  const float* hx_w    = (const float*)d_in[9];
  const float* hx_b    = (const float*)d_in[10];

  char* ws = (char*)d_ws;
  u32*      mall = (u32*)(ws + MALL_OFF);
  u32*      gcv  = (u32*)(ws + GC_OFF);
  u16*      hb   = (u16*)(ws + HB_OFF);
  u16*      wkv  = (u16*)(ws + WK_OFF);
  float*    wxv  = (float*)(ws + WX_OFF);
  float*    wbv  = (float*)(ws + WB_OFF);
  u16*      awv  = (u16*)(ws + AW_OFF);
  float*    abv  = (float*)(ws + AB_OFF);

  hipLaunchKernelGGL(prep_pack, dim3(2052), dim3(64), 0, stream,
                     W_w, W_b, U_w, alpha_w, alpha_b, hx_w, hx_b, wkv, wxv, wbv, awv, abv, mall);
  hipLaunchKernelGGL(lstm_persist, dim3(256), dim3(256), 0, stream,
                     rnn, tau, z0, cz0, wkv, wxv, wbv, awv, abv, hb, mall, gcv, (float*)d_out);
}